// Round 4
// baseline (403.078 us; speedup 1.0000x reference)
//
#include <hip/hip_runtime.h>

typedef unsigned short u16;
typedef unsigned int   u32;
typedef __attribute__((ext_vector_type(8))) __bf16 bf16x8;
typedef __attribute__((ext_vector_type(4))) float  f32x4;

#define HW 4096
#define NPOS 65536
#define CH 256
#define MT 512    // workspace stride (allocation); NMT=256 used
#define NMT 256   // number of 256-row M tiles

__device__ __forceinline__ u16 f2bf(float f){
  u32 u = __float_as_uint(f);
  u += 0x7FFFu + ((u >> 16) & 1u);
  return (u16)(u >> 16);
}
__device__ __forceinline__ float bflo(u32 p){ return __uint_as_float(p << 16); }
__device__ __forceinline__ float bfhi(u32 p){ return __uint_as_float(p & 0xFFFF0000u); }

// global_load_lds width=16: per-lane GLOBAL src, wave-uniform LDS dst + lane*16B.
#define GLL16(g, l) __builtin_amdgcn_global_load_lds( \
    (__attribute__((address_space(1))) void*)(g), \
    (__attribute__((address_space(3))) void*)(l), 16, 0, 0)

#define VM8() asm volatile("s_waitcnt vmcnt(8)" ::: "memory")
#define VM4() asm volatile("s_waitcnt vmcnt(4)" ::: "memory")
#define VM0() asm volatile("s_waitcnt vmcnt(0)" ::: "memory")
#define BARX() do { __builtin_amdgcn_s_barrier(); __builtin_amdgcn_sched_barrier(0); } while(0)

// ---------------- x plane stats: total, edge rows/cols, corners ----------------
__global__ __launch_bounds__(256) void k_statsx(const float* __restrict__ x, float* __restrict__ stats){
  int bc = blockIdx.x; int tid = threadIdx.x;
  const float* xp = x + (size_t)bc * HW;
  float S=0.f, r0=0.f, r1=0.f, c0=0.f, c1=0.f;
  #pragma unroll
  for (int k=0;k<4;k++){
    int i4 = tid + k*256;
    float4 v = ((const float4*)xp)[i4];
    int pos = i4*4; int h = pos>>6; int wb = pos&63;
    float sv = v.x+v.y+v.z+v.w;
    S += sv;
    if (h==0)  r0 += sv;
    if (h==63) r1 += sv;
    if (wb==0)  c0 += v.x;
    if (wb==60) c1 += v.w;
  }
  __shared__ float red[4][5];
  #pragma unroll
  for (int off=32; off>0; off>>=1){
    S  += __shfl_down(S, off);
    r0 += __shfl_down(r0, off);
    r1 += __shfl_down(r1, off);
    c0 += __shfl_down(c0, off);
    c1 += __shfl_down(c1, off);
  }
  if ((tid & 63) == 0){
    int w = tid >> 6;
    red[w][0]=S; red[w][1]=r0; red[w][2]=r1; red[w][3]=c0; red[w][4]=c1;
  }
  __syncthreads();
  if (tid == 0){
    float* o = stats + (size_t)bc * 9;
    for (int j=0;j<5;j++) o[j] = red[0][j]+red[1][j]+red[2][j]+red[3][j];
    o[5] = xp[0];    // x[0][0]
    o[6] = xp[63];   // x[0][63]
    o[7] = xp[4032]; // x[63][0]
    o[8] = xp[4095]; // x[63][63]
  }
}

// ---------------- fused modulation gate: one block per batch element ----------------
__global__ __launch_bounds__(256) void k_gate(const float* __restrict__ dce,
    const float* __restrict__ stats, const float* __restrict__ wch,
    const float* __restrict__ w_dce, const float* __restrict__ b_dce,
    const float* __restrict__ w_sh, const float* __restrict__ b_sh,
    const float* __restrict__ w_ex, const float* __restrict__ b_ex,
    float* __restrict__ modb){
  int b = blockIdx.x, tid = threadIdx.x;
  __shared__ float pl[128];
  __shared__ float mbuf[256];
  __shared__ float hbuf[128];
  __shared__ float ptmp[256];
  {
    int k = tid & 127, half = tid >> 7;
    const float* p = dce + (size_t)b*12800 + half*50*128 + k;
    float s = 0.f;
    #pragma unroll 5
    for (int l=0;l<50;l++) s += p[l*128];
    ptmp[tid] = s;
  }
  __syncthreads();
  if (tid < 128) pl[tid] = (ptmp[tid] + ptmp[tid+128]) * 0.01f;
  __syncthreads();
  {
    int c = tid;
    const float* st = stats + (size_t)(b*256+c)*9;
    float S=st[0], r0=st[1], r1=st[2], cc0=st[3], cc1=st[4];
    float x00=st[5], x0W=st[6], xH0=st[7], xHW=st[8];
    float acc = 0.f;
    #pragma unroll
    for (int t=0;t<9;t++){
      int dh = t/3 - 1, dw = t%3 - 1;
      float R = (dh==1)? r0 : (dh==-1)? r1 : 0.f;
      float Cc = (dw==1)? cc0 : (dw==-1)? cc1 : 0.f;
      float X = 0.f;
      if (dh==1 && dw==1) X = x00;
      else if (dh==1 && dw==-1) X = x0W;
      else if (dh==-1 && dw==1) X = xH0;
      else if (dh==-1 && dw==-1) X = xHW;
      acc += wch[c*9+t] * (S - R - Cc + X);
    }
    float sp_ = acc * (1.f/4096.f);
    float dp = b_dce[c];
    const float4* wr = (const float4*)(w_dce + c*128);
    #pragma unroll 8
    for (int k4=0;k4<32;k4++){
      float4 w4 = wr[k4];
      dp += w4.x*pl[k4*4] + w4.y*pl[k4*4+1] + w4.z*pl[k4*4+2] + w4.w*pl[k4*4+3];
    }
    mbuf[c] = sp_ * dp;
  }
  __syncthreads();
  if (tid < 128){
    int j = tid;
    float acc = b_sh[j];
    const float4* wr = (const float4*)(w_sh + j*256);
    #pragma unroll 8
    for (int k4=0;k4<64;k4++){
      float4 w4 = wr[k4];
      acc += w4.x*mbuf[k4*4] + w4.y*mbuf[k4*4+1] + w4.z*mbuf[k4*4+2] + w4.w*mbuf[k4*4+3];
    }
    hbuf[j] = fmaxf(acc, 0.f);
  }
  __syncthreads();
  {
    int c = tid;
    float acc = b_ex[c];
    const float4* wr = (const float4*)(w_ex + c*128);
    #pragma unroll 8
    for (int k4=0;k4<32;k4++){
      float4 w4 = wr[k4];
      acc += w4.x*hbuf[k4*4] + w4.y*hbuf[k4*4+1] + w4.z*hbuf[k4*4+2] + w4.w*hbuf[k4*4+3];
    }
    modb[b*256+c] = 1.f/(1.f + __expf(-acc));
  }
}

// ---------------- merged weight transforms to bf16 ----------------
__global__ __launch_bounds__(256) void k_wprep(const float* __restrict__ w1,
    const float* __restrict__ wsc, const float* __restrict__ w2,
    u16* __restrict__ w1t, u16* __restrict__ wsct, u16* __restrict__ w2t){
  int bx = blockIdx.x, ci = threadIdx.x;
  if (bx < 2304){
    int co = bx / 9, t = bx - co*9;
    w1t[(size_t)co*2304 + t*256 + ci] = f2bf(w1[(size_t)(co*256+ci)*9 + t]);
  } else if (bx < 2560){
    int i = (bx-2304)*256 + ci;
    wsct[i] = f2bf(wsc[i]);
  } else {
    int i = (bx-2560)*256 + ci;
    w2t[i] = f2bf(w2[i]);
  }
}

// ---------------- xm = x*mod, NCHW f32 -> NHWC bf16 ----------------
__global__ __launch_bounds__(256) void k_xm(const float* __restrict__ x, const float* __restrict__ modb,
                                            u16* __restrict__ xm){
  __shared__ __attribute__((aligned(16))) u16 tile[64*266];
  int pt = blockIdx.x, ct = blockIdx.y, tid = threadIdx.x;
  size_t P0 = (size_t)pt * 256;
  int b = pt >> 4;
  int rem = (pt & 15) << 8;
  int C0 = ct << 6;
  {
    int c = tid >> 2, q = tid & 3;
    const float* xp = x + ((size_t)(b*256 + C0 + c))*HW + rem;
    float mv = modb[b*256 + C0 + c];
    #pragma unroll
    for (int k=0;k<16;k++){
      int pos = q*64 + k*4;
      float4 v = *(const float4*)(xp + pos);
      u32 w0 = (u32)f2bf(v.x*mv) | ((u32)f2bf(v.y*mv) << 16);
      u32 w1 = (u32)f2bf(v.z*mv) | ((u32)f2bf(v.w*mv) << 16);
      u32* dst = (u32*)&tile[c*266 + pos];
      dst[0] = w0; dst[1] = w1;
    }
  }
  __syncthreads();
  {
    int g = tid & 7, p0 = tid >> 3;
    #pragma unroll
    for (int k=0;k<8;k++){
      int pos = p0 + k*32;
      u32 v0 = tile[(g*8+0)*266 + pos], v1 = tile[(g*8+1)*266 + pos];
      u32 v2 = tile[(g*8+2)*266 + pos], v3 = tile[(g*8+3)*266 + pos];
      u32 v4 = tile[(g*8+4)*266 + pos], v5 = tile[(g*8+5)*266 + pos];
      u32 v6 = tile[(g*8+6)*266 + pos], v7 = tile[(g*8+7)*266 + pos];
      uint4 pk;
      pk.x = v0 | (v1<<16); pk.y = v2 | (v3<<16);
      pk.z = v4 | (v5<<16); pk.w = v6 | (v7<<16);
      *(uint4*)(xm + (P0+pos)*CH + C0 + g*8) = pk;
    }
  }
}

// ---------------- 256x256-tile 8-wave GEMM, ONE barrier per K-tile ----------------
// R9: R8 landed 823 TF (MfmaUtil 35) -- 4 barriers/K-tile serialize LDS-read and
// MFMA windows (m233 pattern at phase granularity). Hazard re-derivation with the
// 4-deep set ring shows only ONE barrier + ONE counted vmcnt per K-tile is needed:
//  (a) set w+1 readable: VM(ledger) + tile-end barrier;
//  (b) stage into set (w-1)&3 safe: tile w-1's ds_reads are consumed by MFMAs
//      (lgkmcnt) before those waves reach the tile-end barrier.
// So per tile: 12 ds_read + 4 gload_lds + 32 MFMA between syncs; phase-1 reads sit
// between MFMA clusters with no fence -> compiler's fine-grained lgkmcnt overlaps
// them with cluster-0 MFMAs. Tail ledger: VM8 / VM4(NT-3) / VM0(NT-2) / none.
template<int NTAPS>
__global__ __launch_bounds__(512, 2) void k_gemm8p(const u16* __restrict__ A,
    const u16* __restrict__ Bw, u16* __restrict__ y,
    float* __restrict__ psum, float* __restrict__ psq, const u16* __restrict__ zp){
  constexpr int KTOT = NTAPS*256;
  constexpr int NT = KTOT/32;          // K-tiles
  __shared__ __attribute__((aligned(16))) u16 SH[65536];   // 128 KiB: A 4x8192, B 4x8192 (u16)
  int tid = threadIdx.x;
  int lane = tid & 63, wave = tid >> 6;
  int wm = wave >> 2, wn = wave & 3;
  int l15 = lane & 15, quad = lane >> 4;
  int mt = blockIdx.x;
  int P0 = mt*256;

  // read-side swizzled offsets (u16 units)
  int rdx   = (((l15>>3)&1)<<4) | (((l15>>2)&1)<<3);
  int kphys = (quad*8) ^ rdx;
  int aoff  = (wm*128 + l15)*32 + kphys;          // + set*8192 + i*512 (+2048 for upper half)
  int boff  = 32768 + (wn*64 + l15)*32 + kphys;   // + set*8192 + j*512

  // staging decode: thread writes linear 16B block #tid of the half-tile;
  // inverse swizzle -> source row = tid>>2 (fixed), k-block kb
  int pr = tid >> 2;
  int kb = (tid&3) ^ ((((tid>>5)&1)<<1) | ((tid>>4)&1));
  int k0 = kb*8;
  int pos0 = P0 + pr, pos1 = P0 + 128 + pr;
  int hh0 = (pos0>>6)&63, ww0 = pos0&63;
  int hh1 = (pos1>>6)&63, ww1 = pos1&63;

  f32x4 acc[8][4];
  f32x4 zz = {0.f,0.f,0.f,0.f};
  #pragma unroll
  for (int i=0;i<8;i++)
    #pragma unroll
    for (int j=0;j<4;j++) acc[i][j] = zz;

  auto stageA = [&](int ktn){
    int set = ktn & 3;
    if constexpr (NTAPS == 9){
      int tap = ktn >> 3;
      int t3 = tap/3;
      int dh = t3 - 1, dw = (tap - t3*3) - 1;
      int d = dh*64 + dw;
      int coff = ((ktn & 7)*32) + k0;
      bool ok0 = ((unsigned)(hh0+dh) < 64u) && ((unsigned)(ww0+dw) < 64u);
      bool ok1 = ((unsigned)(hh1+dh) < 64u) && ((unsigned)(ww1+dw) < 64u);
      const u16* s0 = ok0 ? A + (size_t)(pos0 + d)*CH + coff : zp + coff;
      const u16* s1 = ok1 ? A + (size_t)(pos1 + d)*CH + coff : zp + coff;
      GLL16(s0, SH + set*8192 + wave*512);
      GLL16(s1, SH + set*8192 + 4096 + wave*512);
    } else {
      const u16* s0 = A + (size_t)pos0*CH + ktn*32 + k0;
      const u16* s1 = A + (size_t)pos1*CH + ktn*32 + k0;
      GLL16(s0, SH + set*8192 + wave*512);
      GLL16(s1, SH + set*8192 + 4096 + wave*512);
    }
  };
  auto stageB = [&](int ktn){
    int set = ktn & 3;
    const u16* s0 = Bw + (size_t)pr*KTOT + ktn*32 + k0;
    const u16* s1 = Bw + (size_t)(pr+128)*KTOT + ktn*32 + k0;
    GLL16(s0, SH + 32768 + set*8192 + wave*512);
    GLL16(s1, SH + 32768 + set*8192 + 4096 + wave*512);
  };

  // prologue: stage kt 0,1,2 (12 loads/thread); need kt0 -> vmcnt(8)
  stageA(0); stageB(0);
  stageA(1); stageB(1);
  stageA(2); stageB(2);
  VM8();
  BARX();

  for (int w = 0; w < NT; ++w){
    int sb = (w & 3)*8192;
    bf16x8 af[4], bv[4], ag[4];
    #pragma unroll
    for (int i=0;i<4;i++) af[i] = *(const bf16x8*)&SH[sb + aoff + i*512];
    #pragma unroll
    for (int j=0;j<4;j++) bv[j] = *(const bf16x8*)&SH[sb + boff + j*512];
    if (w+3 < NT){ stageA(w+3); stageB(w+3); }
    __builtin_amdgcn_s_setprio(1);
    #pragma unroll
    for (int i=0;i<4;i++)
      #pragma unroll
      for (int j=0;j<4;j++)
        acc[i][j] = __builtin_amdgcn_mfma_f32_16x16x32_bf16(af[i], bv[j], acc[i][j], 0, 0, 0);
    __builtin_amdgcn_s_setprio(0);
    #pragma unroll
    for (int i=0;i<4;i++) ag[i] = *(const bf16x8*)&SH[sb + aoff + 2048 + i*512];
    __builtin_amdgcn_s_setprio(1);
    #pragma unroll
    for (int i=0;i<4;i++)
      #pragma unroll
      for (int j=0;j<4;j++)
        acc[4+i][j] = __builtin_amdgcn_mfma_f32_16x16x32_bf16(ag[i], bv[j], acc[4+i][j], 0, 0, 0);
    __builtin_amdgcn_s_setprio(0);
    if (w < NT-3)      { VM8(); }
    else if (w == NT-3){ VM4(); }
    else if (w == NT-2){ VM0(); }
    BARX();
  }

  // ---- epilogue: y stores + per-mtile channel partials ----
  #pragma unroll
  for (int i=0;i<8;i++){
    int m = wm*128 + i*16 + quad*4;
    #pragma unroll
    for (int j=0;j<4;j++){
      int n = wn*64 + j*16 + l15;
      size_t base = ((size_t)(P0 + m))*CH + n;
      #pragma unroll
      for (int r=0;r<4;r++)
        y[base + (size_t)r*CH] = f2bf(acc[i][j][r]);
    }
  }
  float* SHf = (float*)SH;   // safe: loop-end barrier passed, vmcnt drained
  #pragma unroll
  for (int j=0;j<4;j++){
    float a=0.f, b=0.f;
    #pragma unroll
    for (int i=0;i<8;i++)
      #pragma unroll
      for (int r=0;r<4;r++){ float v = acc[i][j][r]; a += v; b += v*v; }
    a += __shfl_xor(a,16); b += __shfl_xor(b,16);
    a += __shfl_xor(a,32); b += __shfl_xor(b,32);
    if (quad==0){
      int idx = ((wave*4 + j)*16 + l15)*2;
      SHf[idx] = a; SHf[idx+1] = b;
    }
  }
  __syncthreads();
  if (tid < 256){
    int n = tid; int wnn = n>>6; int j = (n>>4)&3; int li = n&15;
    int i0 = (((wnn)*4 + j)*16 + li)*2;        // wm=0 wave = wn
    int i1 = (((4+wnn)*4 + j)*16 + li)*2;      // wm=1 wave = 4+wn
    psum[(size_t)n*NMT + mt] = SHf[i0] + SHf[i1];
    psq [(size_t)n*NMT + mt] = SHf[i0+1] + SHf[i1+1];
  }
}

// ---------------- BN stat finalize: one block per channel, coalesced ----------------
__global__ __launch_bounds__(64) void k_bnstat(const float* __restrict__ psum, const float* __restrict__ psq,
    const float* __restrict__ g, const float* __restrict__ be,
    float* __restrict__ scale, float* __restrict__ shift){
  int c = blockIdx.x, t = threadIdx.x;
  const float* ps = psum + (size_t)c*NMT;
  const float* pq = psq  + (size_t)c*NMT;
  float s=0.f, q=0.f;
  #pragma unroll
  for (int i=0;i<4;i++){ s += ps[t + i*64]; q += pq[t + i*64]; }
  #pragma unroll
  for (int off=32; off>0; off>>=1){
    s += __shfl_down(s, off);
    q += __shfl_down(q, off);
  }
  if (t == 0){
    float mean = s * (1.f/65536.f);
    float var  = q * (1.f/65536.f) - mean*mean;
    float rstd = rsqrtf(var + 1e-5f);
    float sc = g[c]*rstd;
    scale[c] = sc;
    shift[c] = be[c] - mean*sc;
  }
}

// ---------------- bb1 = silu(bn1(y1)) elementwise on NHWC bf16 ----------------
__global__ __launch_bounds__(256) void k_bb(const u16* __restrict__ y1, const float* __restrict__ sc1,
    const float* __restrict__ sh1, u16* __restrict__ bb){
  __shared__ float sc[256], sh[256];
  int tid = threadIdx.x;
  sc[tid] = sc1[tid]; sh[tid] = sh1[tid];
  __syncthreads();
  size_t i = ((size_t)blockIdx.x*256 + tid)*8;
  int c0 = (int)(i & 255);
  uint4 v = *(const uint4*)(y1 + i);
  u32 a[4] = {v.x, v.y, v.z, v.w};
  u32 o[4];
  #pragma unroll
  for (int p=0;p<4;p++){
    float zl = sc[c0+2*p]*bflo(a[p]) + sh[c0+2*p];
    float zh = sc[c0+2*p+1]*bfhi(a[p]) + sh[c0+2*p+1];
    float ol = zl/(1.f+__expf(-zl));
    float oh = zh/(1.f+__expf(-zh));
    o[p] = (u32)f2bf(ol) | ((u32)f2bf(oh) << 16);
  }
  uint4 w; w.x=o[0]; w.y=o[1]; w.z=o[2]; w.w=o[3];
  *(uint4*)(bb + i) = w;
}

// ---------------- out = silu(bn2(y2)+bns(ysc)), NHWC bf16 -> NCHW f32 ----------------
__global__ __launch_bounds__(256) void k_final(const u16* __restrict__ y2, const u16* __restrict__ ysc,
    const float* __restrict__ sc2, const float* __restrict__ sh2,
    const float* __restrict__ scs, const float* __restrict__ shs,
    float* __restrict__ out){
  __shared__ __attribute__((aligned(16))) float tile[64*257];
  __shared__ float l2s[64], l2h[64], lss[64], lsh[64];
  int pt = blockIdx.x, ct = blockIdx.y, tid = threadIdx.x;
  int C0 = ct << 6;
  if (tid < 64){ l2s[tid]=sc2[C0+tid]; l2h[tid]=sh2[C0+tid]; lss[tid]=scs[C0+tid]; lsh[tid]=shs[C0+tid]; }
  __syncthreads();
  size_t P0 = (size_t)pt * 256;
  int b = pt >> 4; int rem = (pt & 15) << 8;
  {
    int g = tid & 7, p0 = tid >> 3;
    for (int k=0;k<8;k++){
      int pos = p0 + k*32;
      size_t off = (P0+pos)*CH + C0 + g*8;
      uint4 va = *(const uint4*)(y2 + off);
      uint4 vb = *(const uint4*)(ysc + off);
      u32 aa[4] = {va.x,va.y,va.z,va.w};
      u32 bv[4] = {vb.x,vb.y,vb.z,vb.w};
      #pragma unroll
      for (int p=0;p<4;p++){
        int c = g*8 + 2*p;
        float z0 = l2s[c]*bflo(aa[p]) + l2h[c] + lss[c]*bflo(bv[p]) + lsh[c];
        float z1 = l2s[c+1]*bfhi(aa[p]) + l2h[c+1] + lss[c+1]*bfhi(bv[p]) + lsh[c+1];
        tile[c*257 + pos]     = z0/(1.f+__expf(-z0));
        tile[(c+1)*257 + pos] = z1/(1.f+__expf(-z1));
      }
    }
  }
  __syncthreads();
  {
    int c = tid >> 2, q = tid & 3;
    float* op = out + ((size_t)(b*256 + C0 + c))*HW + rem;
    #pragma unroll
    for (int k=0;k<16;k++){
      int pos = q*64 + k*4;
      float4 v;
      v.x = tile[c*257 + pos];
      v.y = tile[c*257 + pos + 1];
      v.z = tile[c*257 + pos + 2];
      v.w = tile[c*257 + pos + 3];
      *(float4*)(op + pos) = v;
    }
  }
}

extern "C" void kernel_launch(void* const* d_in, const int* in_sizes, int n_in,
                              void* d_out, int out_size, void* d_ws, size_t ws_size,
                              hipStream_t stream){
  const float* x     = (const float*)d_in[0];
  const float* dce   = (const float*)d_in[1];
  const float* w_dce = (const float*)d_in[2];
  const float* b_dce = (const float*)d_in[3];
  const float* w_ch  = (const float*)d_in[4];
  const float* w_sh  = (const float*)d_in[5];
  const float* b_sh  = (const float*)d_in[6];
  const float* w_ex  = (const float*)d_in[7];
  const float* b_ex  = (const float*)d_in[8];
  const float* w_c1  = (const float*)d_in[9];
  const float* g1    = (const float*)d_in[10];
  const float* be1   = (const float*)d_in[11];
  const float* w_c2  = (const float*)d_in[12];
  const float* g2    = (const float*)d_in[13];
  const float* be2   = (const float*)d_in[14];
  const float* w_s   = (const float*)d_in[15];
  const float* gs    = (const float*)d_in[16];
  const float* bes   = (const float*)d_in[17];
  float* out = (float*)d_out;
  char* ws = (char*)d_ws;

  const size_t NB = (size_t)NPOS*CH*2;   // 32 MiB per bf16 tensor
  u16* xm  = (u16*)(ws);
  u16* y1  = (u16*)(ws + NB);
  u16* ysc = (u16*)(ws + 2*NB);
  u16* bb  = (u16*)(ws + 3*NB);
  char* p = ws + 4*NB;
  u16* w1t   = (u16*)p; p += (size_t)256*2304*2;
  u16* wsct  = (u16*)p; p += (size_t)256*256*2;
  u16* w2t   = (u16*)p; p += (size_t)256*256*2;
  float* statsx = (float*)p; p += (size_t)16*256*9*4;
  float* modb   = (float*)p; p += (size_t)16*256*4;
  float* p1s = (float*)p; p += (size_t)MT*256*4;
  float* p1q = (float*)p; p += (size_t)MT*256*4;
  float* pss = (float*)p; p += (size_t)MT*256*4;
  float* psqv= (float*)p; p += (size_t)MT*256*4;
  float* p2s = (float*)p; p += (size_t)MT*256*4;
  float* p2q = (float*)p; p += (size_t)MT*256*4;
  float* bn1sc = (float*)p; p += 1024;
  float* bn1sh = (float*)p; p += 1024;
  float* bnssc = (float*)p; p += 1024;
  float* bnssh = (float*)p; p += 1024;
  float* bn2sc = (float*)p; p += 1024;
  float* bn2sh = (float*)p; p += 1024;
  u16* zp = (u16*)p; p += 4096;

  hipMemsetAsync(zp, 0, 4096, stream);
  k_statsx<<<4096, 256, 0, stream>>>(x, statsx);
  k_wprep<<<2816, 256, 0, stream>>>(w_c1, w_s, w_c2, w1t, wsct, w2t);
  k_gate<<<16, 256, 0, stream>>>(dce, statsx, w_ch, w_dce, b_dce, w_sh, b_sh, w_ex, b_ex, modb);
  k_xm<<<dim3(256,4), 256, 0, stream>>>(x, modb, xm);
  k_gemm8p<9><<<256, 512, 0, stream>>>(xm, w1t, y1, p1s, p1q, zp);
  k_bnstat<<<256, 64, 0, stream>>>(p1s, p1q, g1, be1, bn1sc, bn1sh);
  k_bb<<<8192, 256, 0, stream>>>(y1, bn1sc, bn1sh, bb);
  k_gemm8p<1><<<256, 512, 0, stream>>>(xm, wsct, ysc, pss, psqv, zp);
  k_bnstat<<<256, 64, 0, stream>>>(pss, psqv, gs, bes, bnssc, bnssh);
  k_gemm8p<1><<<256, 512, 0, stream>>>(bb, w2t, y1 /*=y2*/, p2s, p2q, zp);
  k_bnstat<<<256, 64, 0, stream>>>(p2s, p2q, g2, be2, bn2sc, bn2sh);
  k_final<<<dim3(256,4), 256, 0, stream>>>(y1, ysc, bn2sc, bn2sh, bnssc, bnssh, out);
}

// Round 5
// 389.816 us; speedup vs baseline: 1.0340x; 1.0340x over previous
//
#include <hip/hip_runtime.h>

typedef unsigned short u16;
typedef unsigned int   u32;
typedef __attribute__((ext_vector_type(8))) __bf16 bf16x8;
typedef __attribute__((ext_vector_type(4))) float  f32x4;

#define HW 4096
#define NPOS 65536
#define CH 256
#define MT 512    // workspace stride (allocation); NMT=256 used
#define NMT 256   // number of 256-row M tiles

__device__ __forceinline__ u16 f2bf(float f){
  u32 u = __float_as_uint(f);
  u += 0x7FFFu + ((u >> 16) & 1u);
  return (u16)(u >> 16);
}
__device__ __forceinline__ float bflo(u32 p){ return __uint_as_float(p << 16); }
__device__ __forceinline__ float bfhi(u32 p){ return __uint_as_float(p & 0xFFFF0000u); }

#define GLL16(g, l) __builtin_amdgcn_global_load_lds( \
    (__attribute__((address_space(1))) void*)(g), \
    (__attribute__((address_space(3))) void*)(l), 16, 0, 0)

#define VM4() asm volatile("s_waitcnt vmcnt(4)" ::: "memory")
#define VM0() asm volatile("s_waitcnt vmcnt(0)" ::: "memory")
#define BARX() do { __builtin_amdgcn_s_barrier(); __builtin_amdgcn_sched_barrier(0); } while(0)
#define SP1() __builtin_amdgcn_s_setprio(1)
#define SP0() __builtin_amdgcn_s_setprio(0)

// 16-MFMA quadrant: compile-time indices only (rule #20)
#define MMQ(Aa, Bb, IO, JO) \
  { _Pragma("unroll") for (int fi=0; fi<4; fi++){ \
      _Pragma("unroll") for (int fj=0; fj<2; fj++){ \
        acc[(IO)+fi][(JO)+fj] = __builtin_amdgcn_mfma_f32_16x16x32_bf16(Aa[0][fi], Bb[0][fj], acc[(IO)+fi][(JO)+fj], 0,0,0); \
        acc[(IO)+fi][(JO)+fj] = __builtin_amdgcn_mfma_f32_16x16x32_bf16(Aa[1][fi], Bb[1][fj], acc[(IO)+fi][(JO)+fj], 0,0,0); \
  } } }

#define RDA(dst, D, QOFF) \
  { _Pragma("unroll") for (int fi=0; fi<4; fi++){ \
      dst[0][fi] = *(const bf16x8*)&SH[(D) + aBase + (QOFF) + fi*1024 + kx0]; \
      dst[1][fi] = *(const bf16x8*)&SH[(D) + aBase + (QOFF) + fi*1024 + kx1]; \
  } }
#define RDB(dst, D, JOFF) \
  { _Pragma("unroll") for (int fj=0; fj<2; fj++){ \
      dst[0][fj] = *(const bf16x8*)&SH[(D) + bBase + (JOFF) + fj*1024 + kx0]; \
      dst[1][fj] = *(const bf16x8*)&SH[(D) + bBase + (JOFF) + fj*1024 + kx1]; \
  } }

// ---------------- x plane stats: total, edge rows/cols, corners ----------------
__global__ __launch_bounds__(256) void k_statsx(const float* __restrict__ x, float* __restrict__ stats){
  int bc = blockIdx.x; int tid = threadIdx.x;
  const float* xp = x + (size_t)bc * HW;
  float S=0.f, r0=0.f, r1=0.f, c0=0.f, c1=0.f;
  #pragma unroll
  for (int k=0;k<4;k++){
    int i4 = tid + k*256;
    float4 v = ((const float4*)xp)[i4];
    int pos = i4*4; int h = pos>>6; int wb = pos&63;
    float sv = v.x+v.y+v.z+v.w;
    S += sv;
    if (h==0)  r0 += sv;
    if (h==63) r1 += sv;
    if (wb==0)  c0 += v.x;
    if (wb==60) c1 += v.w;
  }
  __shared__ float red[4][5];
  #pragma unroll
  for (int off=32; off>0; off>>=1){
    S  += __shfl_down(S, off);
    r0 += __shfl_down(r0, off);
    r1 += __shfl_down(r1, off);
    c0 += __shfl_down(c0, off);
    c1 += __shfl_down(c1, off);
  }
  if ((tid & 63) == 0){
    int w = tid >> 6;
    red[w][0]=S; red[w][1]=r0; red[w][2]=r1; red[w][3]=c0; red[w][4]=c1;
  }
  __syncthreads();
  if (tid == 0){
    float* o = stats + (size_t)bc * 9;
    for (int j=0;j<5;j++) o[j] = red[0][j]+red[1][j]+red[2][j]+red[3][j];
    o[5] = xp[0];    // x[0][0]
    o[6] = xp[63];   // x[0][63]
    o[7] = xp[4032]; // x[63][0]
    o[8] = xp[4095]; // x[63][63]
  }
}

// ---------------- fused modulation gate: one block per batch element ----------------
__global__ __launch_bounds__(256) void k_gate(const float* __restrict__ dce,
    const float* __restrict__ stats, const float* __restrict__ wch,
    const float* __restrict__ w_dce, const float* __restrict__ b_dce,
    const float* __restrict__ w_sh, const float* __restrict__ b_sh,
    const float* __restrict__ w_ex, const float* __restrict__ b_ex,
    float* __restrict__ modb){
  int b = blockIdx.x, tid = threadIdx.x;
  __shared__ float pl[128];
  __shared__ float mbuf[256];
  __shared__ float hbuf[128];
  __shared__ float ptmp[256];
  {
    int k = tid & 127, half = tid >> 7;
    const float* p = dce + (size_t)b*12800 + half*50*128 + k;
    float s = 0.f;
    #pragma unroll 5
    for (int l=0;l<50;l++) s += p[l*128];
    ptmp[tid] = s;
  }
  __syncthreads();
  if (tid < 128) pl[tid] = (ptmp[tid] + ptmp[tid+128]) * 0.01f;
  __syncthreads();
  {
    int c = tid;
    const float* st = stats + (size_t)(b*256+c)*9;
    float S=st[0], r0=st[1], r1=st[2], cc0=st[3], cc1=st[4];
    float x00=st[5], x0W=st[6], xH0=st[7], xHW=st[8];
    float acc = 0.f;
    #pragma unroll
    for (int t=0;t<9;t++){
      int dh = t/3 - 1, dw = t%3 - 1;
      float R = (dh==1)? r0 : (dh==-1)? r1 : 0.f;
      float Cc = (dw==1)? cc0 : (dw==-1)? cc1 : 0.f;
      float X = 0.f;
      if (dh==1 && dw==1) X = x00;
      else if (dh==1 && dw==-1) X = x0W;
      else if (dh==-1 && dw==1) X = xH0;
      else if (dh==-1 && dw==-1) X = xHW;
      acc += wch[c*9+t] * (S - R - Cc + X);
    }
    float sp_ = acc * (1.f/4096.f);
    float dp = b_dce[c];
    const float4* wr = (const float4*)(w_dce + c*128);
    #pragma unroll 8
    for (int k4=0;k4<32;k4++){
      float4 w4 = wr[k4];
      dp += w4.x*pl[k4*4] + w4.y*pl[k4*4+1] + w4.z*pl[k4*4+2] + w4.w*pl[k4*4+3];
    }
    mbuf[c] = sp_ * dp;
  }
  __syncthreads();
  if (tid < 128){
    int j = tid;
    float acc = b_sh[j];
    const float4* wr = (const float4*)(w_sh + j*256);
    #pragma unroll 8
    for (int k4=0;k4<64;k4++){
      float4 w4 = wr[k4];
      acc += w4.x*mbuf[k4*4] + w4.y*mbuf[k4*4+1] + w4.z*mbuf[k4*4+2] + w4.w*mbuf[k4*4+3];
    }
    hbuf[j] = fmaxf(acc, 0.f);
  }
  __syncthreads();
  {
    int c = tid;
    float acc = b_ex[c];
    const float4* wr = (const float4*)(w_ex + c*128);
    #pragma unroll 8
    for (int k4=0;k4<32;k4++){
      float4 w4 = wr[k4];
      acc += w4.x*hbuf[k4*4] + w4.y*hbuf[k4*4+1] + w4.z*hbuf[k4*4+2] + w4.w*hbuf[k4*4+3];
    }
    modb[b*256+c] = 1.f/(1.f + __expf(-acc));
  }
}

// ---------------- merged weight transforms to bf16 ----------------
__global__ __launch_bounds__(256) void k_wprep(const float* __restrict__ w1,
    const float* __restrict__ wsc, const float* __restrict__ w2,
    u16* __restrict__ w1t, u16* __restrict__ wsct, u16* __restrict__ w2t){
  int bx = blockIdx.x, ci = threadIdx.x;
  if (bx < 2304){
    int co = bx / 9, t = bx - co*9;
    w1t[(size_t)co*2304 + t*256 + ci] = f2bf(w1[(size_t)(co*256+ci)*9 + t]);
  } else if (bx < 2560){
    int i = (bx-2304)*256 + ci;
    wsct[i] = f2bf(wsc[i]);
  } else {
    int i = (bx-2560)*256 + ci;
    w2t[i] = f2bf(w2[i]);
  }
}

// ---------------- xm = x*mod, NCHW f32 -> NHWC bf16 ----------------
__global__ __launch_bounds__(256) void k_xm(const float* __restrict__ x, const float* __restrict__ modb,
                                            u16* __restrict__ xm){
  __shared__ __attribute__((aligned(16))) u16 tile[64*266];
  int pt = blockIdx.x, ct = blockIdx.y, tid = threadIdx.x;
  size_t P0 = (size_t)pt * 256;
  int b = pt >> 4;
  int rem = (pt & 15) << 8;
  int C0 = ct << 6;
  {
    int c = tid >> 2, q = tid & 3;
    const float* xp = x + ((size_t)(b*256 + C0 + c))*HW + rem;
    float mv = modb[b*256 + C0 + c];
    #pragma unroll
    for (int k=0;k<16;k++){
      int pos = q*64 + k*4;
      float4 v = *(const float4*)(xp + pos);
      u32 w0 = (u32)f2bf(v.x*mv) | ((u32)f2bf(v.y*mv) << 16);
      u32 w1 = (u32)f2bf(v.z*mv) | ((u32)f2bf(v.w*mv) << 16);
      u32* dst = (u32*)&tile[c*266 + pos];
      dst[0] = w0; dst[1] = w1;
    }
  }
  __syncthreads();
  {
    int g = tid & 7, p0 = tid >> 3;
    #pragma unroll
    for (int k=0;k<8;k++){
      int pos = p0 + k*32;
      u32 v0 = tile[(g*8+0)*266 + pos], v1 = tile[(g*8+1)*266 + pos];
      u32 v2 = tile[(g*8+2)*266 + pos], v3 = tile[(g*8+3)*266 + pos];
      u32 v4 = tile[(g*8+4)*266 + pos], v5 = tile[(g*8+5)*266 + pos];
      u32 v6 = tile[(g*8+6)*266 + pos], v7 = tile[(g*8+7)*266 + pos];
      uint4 pk;
      pk.x = v0 | (v1<<16); pk.y = v2 | (v3<<16);
      pk.z = v4 | (v5<<16); pk.w = v6 | (v7<<16);
      *(uint4*)(xm + (P0+pos)*CH + C0 + g*8) = pk;
    }
  }
}

// ---------------- 256x256 8-wave GEMM, m201-class 8-phase BK=64 schedule ----------------
// R10: faithful 8-phase port. BK=64 (128B LDS rows -> 3-bit XOR swizzle, conflict-free
// read: 8 lanes/4-bank group = LDS floor). 2-dbuf x (A 2x128x64 + B 2x128x64) = 128KB.
// Iter = 2 K-tiles (T0 even->buf0, T1->buf1), 8 phases; per phase: {ds_read subtile |
// stage 1 half-tile | [vmcnt @p4/p8] | bar | setprio MFMA x16 | bar}. Quadrant order
// Q00,Q10,Q11,Q01 -> reads/phase 12,8,4,0, min frag liveness. Stage slots: p1:T1.B0,
// p2:T1.B1, p3:T2.A0, p4:T2.A1, p5:T2.B0, p6:T2.B1, p7:T3.A0, p8:T3.A1 (each >=1
// full 2-barrier phase after its region's last read; m201 discipline). vmcnt ledger:
// VM4 @p4 (outstanding=p3,p4) proves T1 landed before p5 reads; VM4 @p8 proves T2
// landed before next p1; last iter p4 -> VM0. Prologue: T0 all + T1.A0/A1, VM4, bar.
template<int NTAPS>
__global__ __launch_bounds__(512, 2) void k_gemm8p(const u16* __restrict__ A,
    const u16* __restrict__ Bw, u16* __restrict__ y,
    float* __restrict__ psum, float* __restrict__ psq, const u16* __restrict__ zp){
  constexpr int KTOT = NTAPS*256;
  constexpr int NT = KTOT/64;          // K-tiles (BK=64)
  constexpr int NI = NT/2;             // iterations (2 tiles each)
  __shared__ __attribute__((aligned(16))) u16 SH[65536];   // A [0,32K), B [32K,64K) u16
  int tid = threadIdx.x;
  int lane = tid & 63, wave = tid >> 6;
  int wm = wave >> 2, wn = wave & 3;
  int l15 = lane & 15, quad = lane >> 4;
  int mt = blockIdx.x;
  int P0 = mt*256;

  // read-side: phys chunk = (ks*4+quad) ^ (row&7); row&7 == l15&7
  int s3  = l15 & 7;
  int kx0 = ((quad)     ^ s3) * 8;
  int kx1 = ((4 | quad) ^ s3) * 8;
  int aBase = wm*8192 + l15*64;                                  // + d + qm*4096 + fi*1024
  int bBase = 32768 + (wn>>1)*8192 + (wn&1)*4096 + l15*64;       // + d + fj*1024

  // staging decode: linear chunk C = L*512+tid -> row=C>>3, pchunk=C&7,
  // logical chunk c0 = pchunk ^ (row&7)  (same for L=0/1 since 64 ≡ 0 mod 8)
  int r0  = tid >> 3;
  int c0  = (tid & 7) ^ (r0 & 7);
  int csrc = c0 * 8;   // u16 offset within the 64-k row

  f32x4 acc[8][4];
  f32x4 zz = {0.f,0.f,0.f,0.f};
  #pragma unroll
  for (int i=0;i<8;i++)
    #pragma unroll
    for (int j=0;j<4;j++) acc[i][j] = zz;

  auto stageA = [&](int t, int ah){
    int base = (t&1)*16384 + ah*8192;
    if constexpr (NTAPS == 9){
      int tap = t >> 2, koff = (t & 3) << 6;
      int t3 = tap/3;
      int dh = t3 - 1, dw = (tap - t3*3) - 1;
      int d = dh*64 + dw;
      #pragma unroll
      for (int L=0; L<2; L++){
        int pos = P0 + ah*128 + (L<<6) + r0;
        int h = (pos>>6)&63, w = pos&63;
        bool ok = ((unsigned)(h+dh) < 64u) && ((unsigned)(w+dw) < 64u);
        const u16* s = ok ? A + (size_t)(pos + d)*CH + koff + csrc : zp + csrc;
        GLL16(s, SH + base + L*4096 + tid*8);
      }
    } else {
      #pragma unroll
      for (int L=0; L<2; L++){
        int pos = P0 + ah*128 + (L<<6) + r0;
        const u16* s = A + (size_t)pos*CH + t*64 + csrc;
        GLL16(s, SH + base + L*4096 + tid*8);
      }
    }
  };
  auto stageB = [&](int t, int bh){
    int base = 32768 + (t&1)*16384 + bh*8192;
    #pragma unroll
    for (int L=0; L<2; L++){
      int co = bh*128 + (L<<6) + r0;
      const u16* s = Bw + (size_t)co*KTOT + t*64 + csrc;
      GLL16(s, SH + base + L*4096 + tid*8);
    }
  };

  // prologue: T0 fully + T1.A halves (12 loads); wait T0 (leave 4 in flight)
  stageA(0,0); stageA(0,1); stageB(0,0); stageB(0,1);
  stageA(1,0); stageA(1,1);
  VM4();
  BARX();

  bf16x8 aLo[2][4], aHi[2][4], bLo[2][2], bHi[2][2];

  for (int n=0; n<NI; ++n){
    const int t1 = 2*n+1;
    const bool pre = (n+1 < NI);
    // ---- p1: read T0 aLo+bLo (12 rd); stage T1.B0 ----
    RDA(aLo, 0, 0); RDB(bLo, 0, 0);
    stageB(t1, 0);
    BARX();
    SP1(); MMQ(aLo, bLo, 0, 0); SP0();
    BARX();
    // ---- p2: read aHi; stage T1.B1 ----
    RDA(aHi, 0, 4096);
    stageB(t1, 1);
    BARX();
    SP1(); MMQ(aHi, bLo, 4, 0); SP0();
    BARX();
    // ---- p3: read bHi; stage T2.A0 ----
    RDB(bHi, 0, 2048);
    if (pre) stageA(t1+1, 0);
    BARX();
    SP1(); MMQ(aHi, bHi, 4, 2); SP0();
    BARX();
    // ---- p4: stage T2.A1; VM4 (T1 landed) ----
    if (pre){ stageA(t1+1, 1); VM4(); } else { VM0(); }
    BARX();
    SP1(); MMQ(aLo, bHi, 0, 2); SP0();
    BARX();
    // ---- p5: read T1 aLo+bLo (buf1); stage T2.B0 ----
    RDA(aLo, 16384, 0); RDB(bLo, 16384, 0);
    if (pre) stageB(t1+1, 0);
    BARX();
    SP1(); MMQ(aLo, bLo, 0, 0); SP0();
    BARX();
    // ---- p6: read aHi; stage T2.B1 ----
    RDA(aHi, 16384, 4096);
    if (pre) stageB(t1+1, 1);
    BARX();
    SP1(); MMQ(aHi, bLo, 4, 0); SP0();
    BARX();
    // ---- p7: read bHi; stage T3.A0 ----
    RDB(bHi, 16384, 2048);
    if (pre) stageA(t1+2, 0);
    BARX();
    SP1(); MMQ(aHi, bHi, 4, 2); SP0();
    BARX();
    // ---- p8: stage T3.A1; VM4 (T2 landed) ----
    if (pre){ stageA(t1+2, 1); VM4(); }
    BARX();
    SP1(); MMQ(aLo, bHi, 0, 2); SP0();
    BARX();
  }

  // ---- epilogue: y stores + per-mtile channel partials ----
  #pragma unroll
  for (int i=0;i<8;i++){
    int m = wm*128 + i*16 + quad*4;
    #pragma unroll
    for (int j=0;j<4;j++){
      int n = wn*64 + j*16 + l15;
      size_t base = ((size_t)(P0 + m))*CH + n;
      #pragma unroll
      for (int r=0;r<4;r++)
        y[base + (size_t)r*CH] = f2bf(acc[i][j][r]);
    }
  }
  float* SHf = (float*)SH;   // safe: loop-end barrier passed, vmcnt drained
  #pragma unroll
  for (int j=0;j<4;j++){
    float a=0.f, b=0.f;
    #pragma unroll
    for (int i=0;i<8;i++)
      #pragma unroll
      for (int r=0;r<4;r++){ float v = acc[i][j][r]; a += v; b += v*v; }
    a += __shfl_xor(a,16); b += __shfl_xor(b,16);
    a += __shfl_xor(a,32); b += __shfl_xor(b,32);
    if (quad==0){
      int idx = ((wave*4 + j)*16 + l15)*2;
      SHf[idx] = a; SHf[idx+1] = b;
    }
  }
  __syncthreads();
  if (tid < 256){
    int n = tid; int wnn = n>>6; int j = (n>>4)&3; int li = n&15;
    int i0 = (((wnn)*4 + j)*16 + li)*2;        // wm=0 wave = wn
    int i1 = (((4+wnn)*4 + j)*16 + li)*2;      // wm=1 wave = 4+wn
    psum[(size_t)n*NMT + mt] = SHf[i0] + SHf[i1];
    psq [(size_t)n*NMT + mt] = SHf[i0+1] + SHf[i1+1];
  }
}

// ---------------- BN stat finalize: one block per channel, coalesced ----------------
__global__ __launch_bounds__(64) void k_bnstat(const float* __restrict__ psum, const float* __restrict__ psq,
    const float* __restrict__ g, const float* __restrict__ be,
    float* __restrict__ scale, float* __restrict__ shift){
  int c = blockIdx.x, t = threadIdx.x;
  const float* ps = psum + (size_t)c*NMT;
  const float* pq = psq  + (size_t)c*NMT;
  float s=0.f, q=0.f;
  #pragma unroll
  for (int i=0;i<4;i++){ s += ps[t + i*64]; q += pq[t + i*64]; }
  #pragma unroll
  for (int off=32; off>0; off>>=1){
    s += __shfl_down(s, off);
    q += __shfl_down(q, off);
  }
  if (t == 0){
    float mean = s * (1.f/65536.f);
    float var  = q * (1.f/65536.f) - mean*mean;
    float rstd = rsqrtf(var + 1e-5f);
    float sc = g[c]*rstd;
    scale[c] = sc;
    shift[c] = be[c] - mean*sc;
  }
}

// ---------------- bb1 = silu(bn1(y1)) elementwise on NHWC bf16 ----------------
__global__ __launch_bounds__(256) void k_bb(const u16* __restrict__ y1, const float* __restrict__ sc1,
    const float* __restrict__ sh1, u16* __restrict__ bb){
  __shared__ float sc[256], sh[256];
  int tid = threadIdx.x;
  sc[tid] = sc1[tid]; sh[tid] = sh1[tid];
  __syncthreads();
  size_t i = ((size_t)blockIdx.x*256 + tid)*8;
  int c0 = (int)(i & 255);
  uint4 v = *(const uint4*)(y1 + i);
  u32 a[4] = {v.x, v.y, v.z, v.w};
  u32 o[4];
  #pragma unroll
  for (int p=0;p<4;p++){
    float zl = sc[c0+2*p]*bflo(a[p]) + sh[c0+2*p];
    float zh = sc[c0+2*p+1]*bfhi(a[p]) + sh[c0+2*p+1];
    float ol = zl/(1.f+__expf(-zl));
    float oh = zh/(1.f+__expf(-zh));
    o[p] = (u32)f2bf(ol) | ((u32)f2bf(oh) << 16);
  }
  uint4 w; w.x=o[0]; w.y=o[1]; w.z=o[2]; w.w=o[3];
  *(uint4*)(bb + i) = w;
}

// ---------------- out = silu(bn2(y2)+bns(ysc)), NHWC bf16 -> NCHW f32 ----------------
__global__ __launch_bounds__(256) void k_final(const u16* __restrict__ y2, const u16* __restrict__ ysc,
    const float* __restrict__ sc2, const float* __restrict__ sh2,
    const float* __restrict__ scs, const float* __restrict__ shs,
    float* __restrict__ out){
  __shared__ __attribute__((aligned(16))) float tile[64*257];
  __shared__ float l2s[64], l2h[64], lss[64], lsh[64];
  int pt = blockIdx.x, ct = blockIdx.y, tid = threadIdx.x;
  int C0 = ct << 6;
  if (tid < 64){ l2s[tid]=sc2[C0+tid]; l2h[tid]=sh2[C0+tid]; lss[tid]=scs[C0+tid]; lsh[tid]=shs[C0+tid]; }
  __syncthreads();
  size_t P0 = (size_t)pt * 256;
  int b = pt >> 4; int rem = (pt & 15) << 8;
  {
    int g = tid & 7, p0 = tid >> 3;
    for (int k=0;k<8;k++){
      int pos = p0 + k*32;
      size_t off = (P0+pos)*CH + C0 + g*8;
      uint4 va = *(const uint4*)(y2 + off);
      uint4 vb = *(const uint4*)(ysc + off);
      u32 aa[4] = {va.x,va.y,va.z,va.w};
      u32 bv[4] = {vb.x,vb.y,vb.z,vb.w};
      #pragma unroll
      for (int p=0;p<4;p++){
        int c = g*8 + 2*p;
        float z0 = l2s[c]*bflo(aa[p]) + l2h[c] + lss[c]*bflo(bv[p]) + lsh[c];
        float z1 = l2s[c+1]*bfhi(aa[p]) + l2h[c+1] + lss[c+1]*bfhi(bv[p]) + lsh[c+1];
        tile[c*257 + pos]     = z0/(1.f+__expf(-z0));
        tile[(c+1)*257 + pos] = z1/(1.f+__expf(-z1));
      }
    }
  }
  __syncthreads();
  {
    int c = tid >> 2, q = tid & 3;
    float* op = out + ((size_t)(b*256 + C0 + c))*HW + rem;
    #pragma unroll
    for (int k=0;k<16;k++){
      int pos = q*64 + k*4;
      float4 v;
      v.x = tile[c*257 + pos];
      v.y = tile[c*257 + pos + 1];
      v.z = tile[c*257 + pos + 2];
      v.w = tile[c*257 + pos + 3];
      *(float4*)(op + pos) = v;
    }
  }
}

extern "C" void kernel_launch(void* const* d_in, const int* in_sizes, int n_in,
                              void* d_out, int out_size, void* d_ws, size_t ws_size,
                              hipStream_t stream){
  const float* x     = (const float*)d_in[0];
  const float* dce   = (const float*)d_in[1];
  const float* w_dce = (const float*)d_in[2];
  const float* b_dce = (const float*)d_in[3];
  const float* w_ch  = (const float*)d_in[4];
  const float* w_sh  = (const float*)d_in[5];
  const float* b_sh  = (const float*)d_in[6];
  const float* w_ex  = (const float*)d_in[7];
  const float* b_ex  = (const float*)d_in[8];
  const float* w_c1  = (const float*)d_in[9];
  const float* g1    = (const float*)d_in[10];
  const float* be1   = (const float*)d_in[11];
  const float* w_c2  = (const float*)d_in[12];
  const float* g2    = (const float*)d_in[13];
  const float* be2   = (const float*)d_in[14];
  const float* w_s   = (const float*)d_in[15];
  const float* gs    = (const float*)d_in[16];
  const float* bes   = (const float*)d_in[17];
  float* out = (float*)d_out;
  char* ws = (char*)d_ws;

  const size_t NB = (size_t)NPOS*CH*2;   // 32 MiB per bf16 tensor
  u16* xm  = (u16*)(ws);
  u16* y1  = (u16*)(ws + NB);
  u16* ysc = (u16*)(ws + 2*NB);
  u16* bb  = (u16*)(ws + 3*NB);
  char* p = ws + 4*NB;
  u16* w1t   = (u16*)p; p += (size_t)256*2304*2;
  u16* wsct  = (u16*)p; p += (size_t)256*256*2;
  u16* w2t   = (u16*)p; p += (size_t)256*256*2;
  float* statsx = (float*)p; p += (size_t)16*256*9*4;
  float* modb   = (float*)p; p += (size_t)16*256*4;
  float* p1s = (float*)p; p += (size_t)MT*256*4;
  float* p1q = (float*)p; p += (size_t)MT*256*4;
  float* pss = (float*)p; p += (size_t)MT*256*4;
  float* psqv= (float*)p; p += (size_t)MT*256*4;
  float* p2s = (float*)p; p += (size_t)MT*256*4;
  float* p2q = (float*)p; p += (size_t)MT*256*4;
  float* bn1sc = (float*)p; p += 1024;
  float* bn1sh = (float*)p; p += 1024;
  float* bnssc = (float*)p; p += 1024;
  float* bnssh = (float*)p; p += 1024;
  float* bn2sc = (float*)p; p += 1024;
  float* bn2sh = (float*)p; p += 1024;
  u16* zp = (u16*)p; p += 4096;

  hipMemsetAsync(zp, 0, 4096, stream);
  k_statsx<<<4096, 256, 0, stream>>>(x, statsx);
  k_wprep<<<2816, 256, 0, stream>>>(w_c1, w_s, w_c2, w1t, wsct, w2t);
  k_gate<<<16, 256, 0, stream>>>(dce, statsx, w_ch, w_dce, b_dce, w_sh, b_sh, w_ex, b_ex, modb);
  k_xm<<<dim3(256,4), 256, 0, stream>>>(x, modb, xm);
  k_gemm8p<9><<<256, 512, 0, stream>>>(xm, w1t, y1, p1s, p1q, zp);
  k_bnstat<<<256, 64, 0, stream>>>(p1s, p1q, g1, be1, bn1sc, bn1sh);
  k_bb<<<8192, 256, 0, stream>>>(y1, bn1sc, bn1sh, bb);
  k_gemm8p<1><<<256, 512, 0, stream>>>(xm, wsct, ysc, pss, psqv, zp);
  k_bnstat<<<256, 64, 0, stream>>>(pss, psqv, gs, bes, bnssc, bnssh);
  k_gemm8p<1><<<256, 512, 0, stream>>>(bb, w2t, y1 /*=y2*/, p2s, p2q, zp);
  k_bnstat<<<256, 64, 0, stream>>>(p2s, p2q, g2, be2, bn2sc, bn2sh);
  k_final<<<dim3(256,4), 256, 0, stream>>>(y1, ysc, bn2sc, bn2sh, bnssc, bnssh, out);
}

// Round 6
// 384.099 us; speedup vs baseline: 1.0494x; 1.0149x over previous
//
#include <hip/hip_runtime.h>

typedef unsigned short u16;
typedef unsigned int   u32;
typedef __attribute__((ext_vector_type(8))) __bf16 bf16x8;
typedef __attribute__((ext_vector_type(4))) float  f32x4;

#define HW 4096
#define NPOS 65536
#define CH 256
#define MT 512    // workspace stride (allocation); NMT=256 used
#define NMT 256   // number of 256-row M tiles
#define PIMG 4356 // padded image positions: 66*66

__device__ __forceinline__ u16 f2bf(float f){
  u32 u = __float_as_uint(f);
  u += 0x7FFFu + ((u >> 16) & 1u);
  return (u16)(u >> 16);
}
__device__ __forceinline__ float bflo(u32 p){ return __uint_as_float(p << 16); }
__device__ __forceinline__ float bfhi(u32 p){ return __uint_as_float(p & 0xFFFF0000u); }

#define GLL16(g, l) __builtin_amdgcn_global_load_lds( \
    (__attribute__((address_space(1))) void*)(g), \
    (__attribute__((address_space(3))) void*)(l), 16, 0, 0)

#define VM4() asm volatile("s_waitcnt vmcnt(4)" ::: "memory")
#define VM0() asm volatile("s_waitcnt vmcnt(0)" ::: "memory")
// R11: plain s_barrier, NO sched_barrier(0) -- m201's verified template uses bare
// s_barrier; sched_barrier pinning (R4/R5) forbids hiding next-phase addr/read
// setup under MFMA windows (m141 over-pinning lesson). Rule #18 doesn't apply:
// no hand-written lgkmcnt asm, compiler manages ds_read->MFMA waits.
#define BAR() __builtin_amdgcn_s_barrier()
#define SP1() __builtin_amdgcn_s_setprio(1)
#define SP0() __builtin_amdgcn_s_setprio(0)

// 16-MFMA quadrant: compile-time indices only (rule #20)
#define MMQ(Aa, Bb, IO, JO) \
  { _Pragma("unroll") for (int fi=0; fi<4; fi++){ \
      _Pragma("unroll") for (int fj=0; fj<2; fj++){ \
        acc[(IO)+fi][(JO)+fj] = __builtin_amdgcn_mfma_f32_16x16x32_bf16(Aa[0][fi], Bb[0][fj], acc[(IO)+fi][(JO)+fj], 0,0,0); \
        acc[(IO)+fi][(JO)+fj] = __builtin_amdgcn_mfma_f32_16x16x32_bf16(Aa[1][fi], Bb[1][fj], acc[(IO)+fi][(JO)+fj], 0,0,0); \
  } } }

#define RDA(dst, D, QOFF) \
  { _Pragma("unroll") for (int fi=0; fi<4; fi++){ \
      dst[0][fi] = *(const bf16x8*)&SH[(D) + aBase + (QOFF) + fi*1024 + kx0]; \
      dst[1][fi] = *(const bf16x8*)&SH[(D) + aBase + (QOFF) + fi*1024 + kx1]; \
  } }
#define RDB(dst, D, JOFF) \
  { _Pragma("unroll") for (int fj=0; fj<2; fj++){ \
      dst[0][fj] = *(const bf16x8*)&SH[(D) + bBase + (JOFF) + fj*1024 + kx0]; \
      dst[1][fj] = *(const bf16x8*)&SH[(D) + bBase + (JOFF) + fj*1024 + kx1]; \
  } }

// ---------------- x plane stats: total, edge rows/cols, corners ----------------
__global__ __launch_bounds__(256) void k_statsx(const float* __restrict__ x, float* __restrict__ stats){
  int bc = blockIdx.x; int tid = threadIdx.x;
  const float* xp = x + (size_t)bc * HW;
  float S=0.f, r0=0.f, r1=0.f, c0=0.f, c1=0.f;
  #pragma unroll
  for (int k=0;k<4;k++){
    int i4 = tid + k*256;
    float4 v = ((const float4*)xp)[i4];
    int pos = i4*4; int h = pos>>6; int wb = pos&63;
    float sv = v.x+v.y+v.z+v.w;
    S += sv;
    if (h==0)  r0 += sv;
    if (h==63) r1 += sv;
    if (wb==0)  c0 += v.x;
    if (wb==60) c1 += v.w;
  }
  __shared__ float red[4][5];
  #pragma unroll
  for (int off=32; off>0; off>>=1){
    S  += __shfl_down(S, off);
    r0 += __shfl_down(r0, off);
    r1 += __shfl_down(r1, off);
    c0 += __shfl_down(c0, off);
    c1 += __shfl_down(c1, off);
  }
  if ((tid & 63) == 0){
    int w = tid >> 6;
    red[w][0]=S; red[w][1]=r0; red[w][2]=r1; red[w][3]=c0; red[w][4]=c1;
  }
  __syncthreads();
  if (tid == 0){
    float* o = stats + (size_t)bc * 9;
    for (int j=0;j<5;j++) o[j] = red[0][j]+red[1][j]+red[2][j]+red[3][j];
    o[5] = xp[0];    // x[0][0]
    o[6] = xp[63];   // x[0][63]
    o[7] = xp[4032]; // x[63][0]
    o[8] = xp[4095]; // x[63][63]
  }
}

// ---------------- fused modulation gate: one block per batch element ----------------
__global__ __launch_bounds__(256) void k_gate(const float* __restrict__ dce,
    const float* __restrict__ stats, const float* __restrict__ wch,
    const float* __restrict__ w_dce, const float* __restrict__ b_dce,
    const float* __restrict__ w_sh, const float* __restrict__ b_sh,
    const float* __restrict__ w_ex, const float* __restrict__ b_ex,
    float* __restrict__ modb){
  int b = blockIdx.x, tid = threadIdx.x;
  __shared__ float pl[128];
  __shared__ float mbuf[256];
  __shared__ float hbuf[128];
  __shared__ float ptmp[256];
  {
    int k = tid & 127, half = tid >> 7;
    const float* p = dce + (size_t)b*12800 + half*50*128 + k;
    float s = 0.f;
    #pragma unroll 5
    for (int l=0;l<50;l++) s += p[l*128];
    ptmp[tid] = s;
  }
  __syncthreads();
  if (tid < 128) pl[tid] = (ptmp[tid] + ptmp[tid+128]) * 0.01f;
  __syncthreads();
  {
    int c = tid;
    const float* st = stats + (size_t)(b*256+c)*9;
    float S=st[0], r0=st[1], r1=st[2], cc0=st[3], cc1=st[4];
    float x00=st[5], x0W=st[6], xH0=st[7], xHW=st[8];
    float acc = 0.f;
    #pragma unroll
    for (int t=0;t<9;t++){
      int dh = t/3 - 1, dw = t%3 - 1;
      float R = (dh==1)? r0 : (dh==-1)? r1 : 0.f;
      float Cc = (dw==1)? cc0 : (dw==-1)? cc1 : 0.f;
      float X = 0.f;
      if (dh==1 && dw==1) X = x00;
      else if (dh==1 && dw==-1) X = x0W;
      else if (dh==-1 && dw==1) X = xH0;
      else if (dh==-1 && dw==-1) X = xHW;
      acc += wch[c*9+t] * (S - R - Cc + X);
    }
    float sp_ = acc * (1.f/4096.f);
    float dp = b_dce[c];
    const float4* wr = (const float4*)(w_dce + c*128);
    #pragma unroll 8
    for (int k4=0;k4<32;k4++){
      float4 w4 = wr[k4];
      dp += w4.x*pl[k4*4] + w4.y*pl[k4*4+1] + w4.z*pl[k4*4+2] + w4.w*pl[k4*4+3];
    }
    mbuf[c] = sp_ * dp;
  }
  __syncthreads();
  if (tid < 128){
    int j = tid;
    float acc = b_sh[j];
    const float4* wr = (const float4*)(w_sh + j*256);
    #pragma unroll 8
    for (int k4=0;k4<64;k4++){
      float4 w4 = wr[k4];
      acc += w4.x*mbuf[k4*4] + w4.y*mbuf[k4*4+1] + w4.z*mbuf[k4*4+2] + w4.w*mbuf[k4*4+3];
    }
    hbuf[j] = fmaxf(acc, 0.f);
  }
  __syncthreads();
  {
    int c = tid;
    float acc = b_ex[c];
    const float4* wr = (const float4*)(w_ex + c*128);
    #pragma unroll 8
    for (int k4=0;k4<32;k4++){
      float4 w4 = wr[k4];
      acc += w4.x*hbuf[k4*4] + w4.y*hbuf[k4*4+1] + w4.z*hbuf[k4*4+2] + w4.w*hbuf[k4*4+3];
    }
    modb[b*256+c] = 1.f/(1.f + __expf(-acc));
  }
}

// ---------------- merged weight transforms to bf16 ----------------
__global__ __launch_bounds__(256) void k_wprep(const float* __restrict__ w1,
    const float* __restrict__ wsc, const float* __restrict__ w2,
    u16* __restrict__ w1t, u16* __restrict__ wsct, u16* __restrict__ w2t){
  int bx = blockIdx.x, ci = threadIdx.x;
  if (bx < 2304){
    int co = bx / 9, t = bx - co*9;
    w1t[(size_t)co*2304 + t*256 + ci] = f2bf(w1[(size_t)(co*256+ci)*9 + t]);
  } else if (bx < 2560){
    int i = (bx-2304)*256 + ci;
    wsct[i] = f2bf(wsc[i]);
  } else {
    int i = (bx-2560)*256 + ci;
    w2t[i] = f2bf(w2[i]);
  }
}

// ---------------- zero the 1-px halo ring of padded xm ----------------
__global__ __launch_bounds__(256) void k_halo(u16* __restrict__ xm){
  int b = blockIdx.x, tid = threadIdx.x;
  uint4 zq = {0u,0u,0u,0u};
  for (int i = tid; i < 260; i += 256){
    int row, col;
    if (i < 66){ row = 0; col = i; }
    else if (i < 132){ row = 65; col = i - 66; }
    else { int j = i - 132; row = 1 + (j >> 1); col = (j & 1) * 65; }
    uint4* p = (uint4*)(xm + ((size_t)b*PIMG + row*66 + col)*256);
    #pragma unroll
    for (int q=0;q<32;q++) p[q] = zq;
  }
}

// ---------------- xm = x*mod, NCHW f32 -> padded NHWC bf16 [16][66][66][256] ----------------
__global__ __launch_bounds__(256) void k_xm(const float* __restrict__ x, const float* __restrict__ modb,
                                            u16* __restrict__ xm){
  __shared__ __attribute__((aligned(16))) u16 tile[64*266];
  int pt = blockIdx.x, ct = blockIdx.y, tid = threadIdx.x;
  int b = pt >> 4;
  int rem = (pt & 15) << 8;
  int C0 = ct << 6;
  {
    int c = tid >> 2, q = tid & 3;
    const float* xp = x + ((size_t)(b*256 + C0 + c))*HW + rem;
    float mv = modb[b*256 + C0 + c];
    #pragma unroll
    for (int k=0;k<16;k++){
      int pos = q*64 + k*4;
      float4 v = *(const float4*)(xp + pos);
      u32 w0 = (u32)f2bf(v.x*mv) | ((u32)f2bf(v.y*mv) << 16);
      u32 w1 = (u32)f2bf(v.z*mv) | ((u32)f2bf(v.w*mv) << 16);
      u32* dst = (u32*)&tile[c*266 + pos];
      dst[0] = w0; dst[1] = w1;
    }
  }
  __syncthreads();
  {
    int g = tid & 7, p0 = tid >> 3;
    #pragma unroll
    for (int k=0;k<8;k++){
      int pos = p0 + k*32;
      u32 v0 = tile[(g*8+0)*266 + pos], v1 = tile[(g*8+1)*266 + pos];
      u32 v2 = tile[(g*8+2)*266 + pos], v3 = tile[(g*8+3)*266 + pos];
      u32 v4 = tile[(g*8+4)*266 + pos], v5 = tile[(g*8+5)*266 + pos];
      u32 v6 = tile[(g*8+6)*266 + pos], v7 = tile[(g*8+7)*266 + pos];
      uint4 pk;
      pk.x = v0 | (v1<<16); pk.y = v2 | (v3<<16);
      pk.z = v4 | (v5<<16); pk.w = v6 | (v7<<16);
      int gp = rem + pos;
      int h = gp >> 6, w = gp & 63;
      *(uint4*)(xm + ((size_t)b*PIMG + (h+1)*66 + (w+1))*256 + C0 + g*8) = pk;
    }
  }
}

// ---------------- 256x256 8-wave GEMM, 8-phase BK=64 (m201 class) ----------------
// R10 verified the schedule (conflicts 0). R11: (a) bare s_barrier (no sched pin);
// (b) padded-A addressing: per-stage source = A + uniform(t) + fixed-thread-voff.
// uniform(t) is SALU (tap=t>>2, t3=(tap*11)>>5, paddelta=tap+63*t3-67), so the
// staging call is saddr-form global_load_lds with zero per-call VALU. No bounds
// check, no zp. vmcnt ledger unchanged: VM4@p4 (T1 landed), VM4@p8 (T2 landed),
// last-iter p4 -> VM0.  APAD: A indexed in padded [b][66][66][256] space.
template<int NTAPS, int APAD>
__global__ __launch_bounds__(512, 2) void k_gemm8p(const u16* __restrict__ A,
    const u16* __restrict__ Bw, u16* __restrict__ y,
    float* __restrict__ psum, float* __restrict__ psq){
  constexpr int KTOT = NTAPS*256;
  constexpr int NT = KTOT/64;          // K-tiles (BK=64)
  constexpr int NI = NT/2;             // iterations (2 tiles each)
  __shared__ __attribute__((aligned(16))) u16 SH[65536];   // A [0,32K), B [32K,64K) u16
  int tid = threadIdx.x;
  int lane = tid & 63, wave = tid >> 6;
  int wm = wave >> 2, wn = wave & 3;
  int l15 = lane & 15, quad = lane >> 4;
  int mt = blockIdx.x;
  int P0 = mt*256;

  // read-side: phys chunk = (ks*4+quad) ^ (row&7); row&7 == l15&7
  int s3  = l15 & 7;
  int kx0 = ((quad)     ^ s3) * 8;
  int kx1 = ((4 | quad) ^ s3) * 8;
  int aBase = wm*8192 + l15*64;                                  // + d + qm*4096 + fi*1024
  int bBase = 32768 + (wn>>1)*8192 + (wn&1)*4096 + l15*64;       // + d + fj*1024

  // staging decode: linear chunk = tid -> row=tid>>3, logical chunk c0=pchunk^(row&7)
  int r0  = tid >> 3;
  int csrc = ((tid & 7) ^ (r0 & 7)) * 8;

  // fixed per-thread source voffsets (u16 units)
  auto pvoff = [&](int pos)->int{
    if constexpr (APAD){
      int b_ = pos >> 12, rm = pos & 4095;
      return (b_*PIMG + ((rm>>6)+1)*66 + (rm&63)+1)*256 + csrc;
    } else {
      return pos*256 + csrc;
    }
  };
  const int vA00 = pvoff(P0 + r0),        vA01 = pvoff(P0 + 64 + r0);
  const int vA10 = pvoff(P0 + 128 + r0),  vA11 = pvoff(P0 + 192 + r0);
  const int vB00 = (r0)*KTOT + csrc,       vB01 = (64 + r0)*KTOT + csrc;
  const int vB10 = (128 + r0)*KTOT + csrc, vB11 = (192 + r0)*KTOT + csrc;

  f32x4 acc[8][4];
  f32x4 zz = {0.f,0.f,0.f,0.f};
  #pragma unroll
  for (int i=0;i<8;i++)
    #pragma unroll
    for (int j=0;j<4;j++) acc[i][j] = zz;

  auto stageA = [&](int t, int ah){
    int base = (t&1)*16384 + ah*8192;
    int uoff;
    if constexpr (NTAPS == 9){
      int tap = t >> 2, t3 = (tap*11) >> 5;           // t3 = tap/3
      uoff = (tap + 63*t3 - 67)*256 + (t&3)*64;       // padded tap delta * 256 + koff
    } else {
      uoff = t*64;
    }
    GLL16(A + uoff + (ah ? vA10 : vA00), SH + base + tid*8);
    GLL16(A + uoff + (ah ? vA11 : vA01), SH + base + 4096 + tid*8);
  };
  auto stageB = [&](int t, int bh){
    int base = 32768 + (t&1)*16384 + bh*8192;
    int uoff = t*64;
    GLL16(Bw + uoff + (bh ? vB10 : vB00), SH + base + tid*8);
    GLL16(Bw + uoff + (bh ? vB11 : vB01), SH + base + 4096 + tid*8);
  };

  // prologue: T0 fully + T1.A halves (12 loads); wait T0 (leave 4 in flight)
  stageA(0,0); stageA(0,1); stageB(0,0); stageB(0,1);
  stageA(1,0); stageA(1,1);
  VM4();
  BAR();

  bf16x8 aLo[2][4], aHi[2][4], bLo[2][2], bHi[2][2];

  for (int n=0; n<NI; ++n){
    const int t1 = 2*n+1;
    const bool pre = (n+1 < NI);
    // ---- p1: read T0 aLo+bLo (12 rd); stage T1.B0 ----
    RDA(aLo, 0, 0); RDB(bLo, 0, 0);
    stageB(t1, 0);
    BAR();
    SP1(); MMQ(aLo, bLo, 0, 0); SP0();
    BAR();
    // ---- p2: read aHi; stage T1.B1 ----
    RDA(aHi, 0, 4096);
    stageB(t1, 1);
    BAR();
    SP1(); MMQ(aHi, bLo, 4, 0); SP0();
    BAR();
    // ---- p3: read bHi; stage T2.A0 ----
    RDB(bHi, 0, 2048);
    if (pre) stageA(t1+1, 0);
    BAR();
    SP1(); MMQ(aHi, bHi, 4, 2); SP0();
    BAR();
    // ---- p4: stage T2.A1; VM4 (T1 landed) ----
    if (pre){ stageA(t1+1, 1); VM4(); } else { VM0(); }
    BAR();
    SP1(); MMQ(aLo, bHi, 0, 2); SP0();
    BAR();
    // ---- p5: read T1 aLo+bLo (buf1); stage T2.B0 ----
    RDA(aLo, 16384, 0); RDB(bLo, 16384, 0);
    if (pre) stageB(t1+1, 0);
    BAR();
    SP1(); MMQ(aLo, bLo, 0, 0); SP0();
    BAR();
    // ---- p6: read aHi; stage T2.B1 ----
    RDA(aHi, 16384, 4096);
    if (pre) stageB(t1+1, 1);
    BAR();
    SP1(); MMQ(aHi, bLo, 4, 0); SP0();
    BAR();
    // ---- p7: read bHi; stage T3.A0 ----
    RDB(bHi, 16384, 2048);
    if (pre) stageA(t1+2, 0);
    BAR();
    SP1(); MMQ(aHi, bHi, 4, 2); SP0();
    BAR();
    // ---- p8: stage T3.A1; VM4 (T2 landed) ----
    if (pre){ stageA(t1+2, 1); VM4(); }
    BAR();
    SP1(); MMQ(aLo, bHi, 0, 2); SP0();
    BAR();
  }

  // ---- epilogue: y stores + per-mtile channel partials ----
  #pragma unroll
  for (int i=0;i<8;i++){
    int m = wm*128 + i*16 + quad*4;
    #pragma unroll
    for (int j=0;j<4;j++){
      int n = wn*64 + j*16 + l15;
      size_t base = ((size_t)(P0 + m))*CH + n;
      #pragma unroll
      for (int r=0;r<4;r++)
        y[base + (size_t)r*CH] = f2bf(acc[i][j][r]);
    }
  }
  float* SHf = (float*)SH;   // safe: loop-end barrier passed, vmcnt drained
  #pragma unroll
  for (int j=0;j<4;j++){
    float a=0.f, b=0.f;
    #pragma unroll
    for (int i=0;i<8;i++)
      #pragma unroll
      for (int r=0;r<4;r++){ float v = acc[i][j][r]; a += v; b += v*v; }
    a += __shfl_xor(a,16); b += __shfl_xor(b,16);
    a += __shfl_xor(a,32); b += __shfl_xor(b,32);
    if (quad==0){
      int idx = ((wave*4 + j)*16 + l15)*2;
      SHf[idx] = a; SHf[idx+1] = b;
    }
  }
  __syncthreads();
  if (tid < 256){
    int n = tid; int wnn = n>>6; int j = (n>>4)&3; int li = n&15;
    int i0 = (((wnn)*4 + j)*16 + li)*2;        // wm=0 wave = wn
    int i1 = (((4+wnn)*4 + j)*16 + li)*2;      // wm=1 wave = 4+wn
    psum[(size_t)n*NMT + mt] = SHf[i0] + SHf[i1];
    psq [(size_t)n*NMT + mt] = SHf[i0+1] + SHf[i1+1];
  }
}

// ---------------- BN stat finalize: one block per channel, coalesced ----------------
__global__ __launch_bounds__(64) void k_bnstat(const float* __restrict__ psum, const float* __restrict__ psq,
    const float* __restrict__ g, const float* __restrict__ be,
    float* __restrict__ scale, float* __restrict__ shift){
  int c = blockIdx.x, t = threadIdx.x;
  const float* ps = psum + (size_t)c*NMT;
  const float* pq = psq  + (size_t)c*NMT;
  float s=0.f, q=0.f;
  #pragma unroll
  for (int i=0;i<4;i++){ s += ps[t + i*64]; q += pq[t + i*64]; }
  #pragma unroll
  for (int off=32; off>0; off>>=1){
    s += __shfl_down(s, off);
    q += __shfl_down(q, off);
  }
  if (t == 0){
    float mean = s * (1.f/65536.f);
    float var  = q * (1.f/65536.f) - mean*mean;
    float rstd = rsqrtf(var + 1e-5f);
    float sc = g[c]*rstd;
    scale[c] = sc;
    shift[c] = be[c] - mean*sc;
  }
}

// ---------------- bb1 = silu(bn1(y1)) elementwise on NHWC bf16 ----------------
__global__ __launch_bounds__(256) void k_bb(const u16* __restrict__ y1, const float* __restrict__ sc1,
    const float* __restrict__ sh1, u16* __restrict__ bb){
  __shared__ float sc[256], sh[256];
  int tid = threadIdx.x;
  sc[tid] = sc1[tid]; sh[tid] = sh1[tid];
  __syncthreads();
  size_t i = ((size_t)blockIdx.x*256 + tid)*8;
  int c0 = (int)(i & 255);
  uint4 v = *(const uint4*)(y1 + i);
  u32 a[4] = {v.x, v.y, v.z, v.w};
  u32 o[4];
  #pragma unroll
  for (int p=0;p<4;p++){
    float zl = sc[c0+2*p]*bflo(a[p]) + sh[c0+2*p];
    float zh = sc[c0+2*p+1]*bfhi(a[p]) + sh[c0+2*p+1];
    float ol = zl/(1.f+__expf(-zl));
    float oh = zh/(1.f+__expf(-zh));
    o[p] = (u32)f2bf(ol) | ((u32)f2bf(oh) << 16);
  }
  uint4 w; w.x=o[0]; w.y=o[1]; w.z=o[2]; w.w=o[3];
  *(uint4*)(bb + i) = w;
}

// ---------------- out = silu(bn2(y2)+bns(ysc)), NHWC bf16 -> NCHW f32 ----------------
__global__ __launch_bounds__(256) void k_final(const u16* __restrict__ y2, const u16* __restrict__ ysc,
    const float* __restrict__ sc2, const float* __restrict__ sh2,
    const float* __restrict__ scs, const float* __restrict__ shs,
    float* __restrict__ out){
  __shared__ __attribute__((aligned(16))) float tile[64*257];
  __shared__ float l2s[64], l2h[64], lss[64], lsh[64];
  int pt = blockIdx.x, ct = blockIdx.y, tid = threadIdx.x;
  int C0 = ct << 6;
  if (tid < 64){ l2s[tid]=sc2[C0+tid]; l2h[tid]=sh2[C0+tid]; lss[tid]=scs[C0+tid]; lsh[tid]=shs[C0+tid]; }
  __syncthreads();
  size_t P0 = (size_t)pt * 256;
  int b = pt >> 4; int rem = (pt & 15) << 8;
  {
    int g = tid & 7, p0 = tid >> 3;
    for (int k=0;k<8;k++){
      int pos = p0 + k*32;
      size_t off = (P0+pos)*CH + C0 + g*8;
      uint4 va = *(const uint4*)(y2 + off);
      uint4 vb = *(const uint4*)(ysc + off);
      u32 aa[4] = {va.x,va.y,va.z,va.w};
      u32 bv[4] = {vb.x,vb.y,vb.z,vb.w};
      #pragma unroll
      for (int p=0;p<4;p++){
        int c = g*8 + 2*p;
        float z0 = l2s[c]*bflo(aa[p]) + l2h[c] + lss[c]*bflo(bv[p]) + lsh[c];
        float z1 = l2s[c+1]*bfhi(aa[p]) + l2h[c+1] + lss[c+1]*bfhi(bv[p]) + lsh[c+1];
        tile[c*257 + pos]     = z0/(1.f+__expf(-z0));
        tile[(c+1)*257 + pos] = z1/(1.f+__expf(-z1));
      }
    }
  }
  __syncthreads();
  {
    int c = tid >> 2, q = tid & 3;
    float* op = out + ((size_t)(b*256 + C0 + c))*HW + rem;
    #pragma unroll
    for (int k=0;k<16;k++){
      int pos = q*64 + k*4;
      float4 v;
      v.x = tile[c*257 + pos];
      v.y = tile[c*257 + pos + 1];
      v.z = tile[c*257 + pos + 2];
      v.w = tile[c*257 + pos + 3];
      *(float4*)(op + pos) = v;
    }
  }
}

extern "C" void kernel_launch(void* const* d_in, const int* in_sizes, int n_in,
                              void* d_out, int out_size, void* d_ws, size_t ws_size,
                              hipStream_t stream){
  const float* x     = (const float*)d_in[0];
  const float* dce   = (const float*)d_in[1];
  const float* w_dce = (const float*)d_in[2];
  const float* b_dce = (const float*)d_in[3];
  const float* w_ch  = (const float*)d_in[4];
  const float* w_sh  = (const float*)d_in[5];
  const float* b_sh  = (const float*)d_in[6];
  const float* w_ex  = (const float*)d_in[7];
  const float* b_ex  = (const float*)d_in[8];
  const float* w_c1  = (const float*)d_in[9];
  const float* g1    = (const float*)d_in[10];
  const float* be1   = (const float*)d_in[11];
  const float* w_c2  = (const float*)d_in[12];
  const float* g2    = (const float*)d_in[13];
  const float* be2   = (const float*)d_in[14];
  const float* w_s   = (const float*)d_in[15];
  const float* gs    = (const float*)d_in[16];
  const float* bes   = (const float*)d_in[17];
  float* out = (float*)d_out;
  char* ws = (char*)d_ws;

  const size_t NB  = (size_t)NPOS*CH*2;        // 32 MiB per bf16 tensor
  const size_t XMB = (size_t)16*PIMG*CH*2;     // padded xm, ~35.7 MiB
  u16* xm  = (u16*)(ws);
  u16* y1  = (u16*)(ws + XMB);
  u16* ysc = (u16*)(ws + XMB + NB);
  u16* bb  = (u16*)(ws + XMB + 2*NB);
  char* p = ws + XMB + 3*NB;
  u16* w1t   = (u16*)p; p += (size_t)256*2304*2;
  u16* wsct  = (u16*)p; p += (size_t)256*256*2;
  u16* w2t   = (u16*)p; p += (size_t)256*256*2;
  float* statsx = (float*)p; p += (size_t)16*256*9*4;
  float* modb   = (float*)p; p += (size_t)16*256*4;
  float* p1s = (float*)p; p += (size_t)MT*256*4;
  float* p1q = (float*)p; p += (size_t)MT*256*4;
  float* pss = (float*)p; p += (size_t)MT*256*4;
  float* psqv= (float*)p; p += (size_t)MT*256*4;
  float* p2s = (float*)p; p += (size_t)MT*256*4;
  float* p2q = (float*)p; p += (size_t)MT*256*4;
  float* bn1sc = (float*)p; p += 1024;
  float* bn1sh = (float*)p; p += 1024;
  float* bnssc = (float*)p; p += 1024;
  float* bnssh = (float*)p; p += 1024;
  float* bn2sc = (float*)p; p += 1024;
  float* bn2sh = (float*)p; p += 1024;

  k_halo<<<16, 256, 0, stream>>>(xm);
  k_statsx<<<4096, 256, 0, stream>>>(x, statsx);
  k_wprep<<<2816, 256, 0, stream>>>(w_c1, w_s, w_c2, w1t, wsct, w2t);
  k_gate<<<16, 256, 0, stream>>>(dce, statsx, w_ch, w_dce, b_dce, w_sh, b_sh, w_ex, b_ex, modb);
  k_xm<<<dim3(256,4), 256, 0, stream>>>(x, modb, xm);
  k_gemm8p<9,1><<<256, 512, 0, stream>>>(xm, w1t, y1, p1s, p1q);
  k_bnstat<<<256, 64, 0, stream>>>(p1s, p1q, g1, be1, bn1sc, bn1sh);
  k_bb<<<8192, 256, 0, stream>>>(y1, bn1sc, bn1sh, bb);
  k_gemm8p<1,1><<<256, 512, 0, stream>>>(xm, wsct, ysc, pss, psqv);
  k_bnstat<<<256, 64, 0, stream>>>(pss, psqv, gs, bes, bnssc, bnssh);
  k_gemm8p<1,0><<<256, 512, 0, stream>>>(bb, w2t, y1 /*=y2*/, p2s, p2q);
  k_bnstat<<<256, 64, 0, stream>>>(p2s, p2q, g2, be2, bn2sc, bn2sh);
  k_final<<<dim3(256,4), 256, 0, stream>>>(y1, ysc, bn2sc, bn2sh, bnssc, bnssh, out);
}

// Round 7
// 379.139 us; speedup vs baseline: 1.0631x; 1.0131x over previous
//
#include <hip/hip_runtime.h>

typedef unsigned short u16;
typedef unsigned int   u32;
typedef __attribute__((ext_vector_type(8))) __bf16 bf16x8;
typedef __attribute__((ext_vector_type(4))) float  f32x4;

#define HW 4096
#define NPOS 65536
#define CH 256
#define MT 512    // workspace stride (allocation); NMT=256 used
#define NMT 256   // number of 256-row M tiles
#define PIMG 4356 // padded image positions: 66*66

__device__ __forceinline__ u16 f2bf(float f){
  u32 u = __float_as_uint(f);
  u += 0x7FFFu + ((u >> 16) & 1u);
  return (u16)(u >> 16);
}
__device__ __forceinline__ float bflo(u32 p){ return __uint_as_float(p << 16); }
__device__ __forceinline__ float bfhi(u32 p){ return __uint_as_float(p & 0xFFFF0000u); }

#define GLL16(g, l) __builtin_amdgcn_global_load_lds( \
    (__attribute__((address_space(1))) void*)(g), \
    (__attribute__((address_space(3))) void*)(l), 16, 0, 0)

#define VM4() asm volatile("s_waitcnt vmcnt(4)" ::: "memory")
#define VM0() asm volatile("s_waitcnt vmcnt(0)" ::: "memory")
#define BAR() __builtin_amdgcn_s_barrier()
#define SP1() __builtin_amdgcn_s_setprio(1)
#define SP0() __builtin_amdgcn_s_setprio(0)

// 16-MFMA quadrant: compile-time indices only (rule #20)
#define MMQ(Aa, Bb, IO, JO) \
  { _Pragma("unroll") for (int fi=0; fi<4; fi++){ \
      _Pragma("unroll") for (int fj=0; fj<2; fj++){ \
        acc[(IO)+fi][(JO)+fj] = __builtin_amdgcn_mfma_f32_16x16x32_bf16(Aa[0][fi], Bb[0][fj], acc[(IO)+fi][(JO)+fj], 0,0,0); \
        acc[(IO)+fi][(JO)+fj] = __builtin_amdgcn_mfma_f32_16x16x32_bf16(Aa[1][fi], Bb[1][fj], acc[(IO)+fi][(JO)+fj], 0,0,0); \
  } } }

#define RDA(dst, D, QOFF) \
  { _Pragma("unroll") for (int fi=0; fi<4; fi++){ \
      dst[0][fi] = *(const bf16x8*)&SH[(D) + aBase + (QOFF) + fi*1024 + kx0]; \
      dst[1][fi] = *(const bf16x8*)&SH[(D) + aBase + (QOFF) + fi*1024 + kx1]; \
  } }
#define RDB(dst, D, JOFF) \
  { _Pragma("unroll") for (int fj=0; fj<2; fj++){ \
      dst[0][fj] = *(const bf16x8*)&SH[(D) + bBase + (JOFF) + fj*1024 + kx0]; \
      dst[1][fj] = *(const bf16x8*)&SH[(D) + bBase + (JOFF) + fj*1024 + kx1]; \
  } }

// ---------------- x plane stats: total, edge rows/cols, corners ----------------
__global__ __launch_bounds__(256) void k_statsx(const float* __restrict__ x, float* __restrict__ stats){
  int bc = blockIdx.x; int tid = threadIdx.x;
  const float* xp = x + (size_t)bc * HW;
  float S=0.f, r0=0.f, r1=0.f, c0=0.f, c1=0.f;
  #pragma unroll
  for (int k=0;k<4;k++){
    int i4 = tid + k*256;
    float4 v = ((const float4*)xp)[i4];
    int pos = i4*4; int h = pos>>6; int wb = pos&63;
    float sv = v.x+v.y+v.z+v.w;
    S += sv;
    if (h==0)  r0 += sv;
    if (h==63) r1 += sv;
    if (wb==0)  c0 += v.x;
    if (wb==60) c1 += v.w;
  }
  __shared__ float red[4][5];
  #pragma unroll
  for (int off=32; off>0; off>>=1){
    S  += __shfl_down(S, off);
    r0 += __shfl_down(r0, off);
    r1 += __shfl_down(r1, off);
    c0 += __shfl_down(c0, off);
    c1 += __shfl_down(c1, off);
  }
  if ((tid & 63) == 0){
    int w = tid >> 6;
    red[w][0]=S; red[w][1]=r0; red[w][2]=r1; red[w][3]=c0; red[w][4]=c1;
  }
  __syncthreads();
  if (tid == 0){
    float* o = stats + (size_t)bc * 9;
    for (int j=0;j<5;j++) o[j] = red[0][j]+red[1][j]+red[2][j]+red[3][j];
    o[5] = xp[0];    // x[0][0]
    o[6] = xp[63];   // x[0][63]
    o[7] = xp[4032]; // x[63][0]
    o[8] = xp[4095]; // x[63][63]
  }
}

// ---------------- fused modulation gate: one block per batch element ----------------
__global__ __launch_bounds__(256) void k_gate(const float* __restrict__ dce,
    const float* __restrict__ stats, const float* __restrict__ wch,
    const float* __restrict__ w_dce, const float* __restrict__ b_dce,
    const float* __restrict__ w_sh, const float* __restrict__ b_sh,
    const float* __restrict__ w_ex, const float* __restrict__ b_ex,
    float* __restrict__ modb){
  int b = blockIdx.x, tid = threadIdx.x;
  __shared__ float pl[128];
  __shared__ float mbuf[256];
  __shared__ float hbuf[128];
  __shared__ float ptmp[256];
  {
    int k = tid & 127, half = tid >> 7;
    const float* p = dce + (size_t)b*12800 + half*50*128 + k;
    float s = 0.f;
    #pragma unroll 5
    for (int l=0;l<50;l++) s += p[l*128];
    ptmp[tid] = s;
  }
  __syncthreads();
  if (tid < 128) pl[tid] = (ptmp[tid] + ptmp[tid+128]) * 0.01f;
  __syncthreads();
  {
    int c = tid;
    const float* st = stats + (size_t)(b*256+c)*9;
    float S=st[0], r0=st[1], r1=st[2], cc0=st[3], cc1=st[4];
    float x00=st[5], x0W=st[6], xH0=st[7], xHW=st[8];
    float acc = 0.f;
    #pragma unroll
    for (int t=0;t<9;t++){
      int dh = t/3 - 1, dw = t%3 - 1;
      float R = (dh==1)? r0 : (dh==-1)? r1 : 0.f;
      float Cc = (dw==1)? cc0 : (dw==-1)? cc1 : 0.f;
      float X = 0.f;
      if (dh==1 && dw==1) X = x00;
      else if (dh==1 && dw==-1) X = x0W;
      else if (dh==-1 && dw==1) X = xH0;
      else if (dh==-1 && dw==-1) X = xHW;
      acc += wch[c*9+t] * (S - R - Cc + X);
    }
    float sp_ = acc * (1.f/4096.f);
    float dp = b_dce[c];
    const float4* wr = (const float4*)(w_dce + c*128);
    #pragma unroll 8
    for (int k4=0;k4<32;k4++){
      float4 w4 = wr[k4];
      dp += w4.x*pl[k4*4] + w4.y*pl[k4*4+1] + w4.z*pl[k4*4+2] + w4.w*pl[k4*4+3];
    }
    mbuf[c] = sp_ * dp;
  }
  __syncthreads();
  if (tid < 128){
    int j = tid;
    float acc = b_sh[j];
    const float4* wr = (const float4*)(w_sh + j*256);
    #pragma unroll 8
    for (int k4=0;k4<64;k4++){
      float4 w4 = wr[k4];
      acc += w4.x*mbuf[k4*4] + w4.y*mbuf[k4*4+1] + w4.z*mbuf[k4*4+2] + w4.w*mbuf[k4*4+3];
    }
    hbuf[j] = fmaxf(acc, 0.f);
  }
  __syncthreads();
  {
    int c = tid;
    float acc = b_ex[c];
    const float4* wr = (const float4*)(w_ex + c*128);
    #pragma unroll 8
    for (int k4=0;k4<32;k4++){
      float4 w4 = wr[k4];
      acc += w4.x*hbuf[k4*4] + w4.y*hbuf[k4*4+1] + w4.z*hbuf[k4*4+2] + w4.w*hbuf[k4*4+3];
    }
    modb[b*256+c] = 1.f/(1.f + __expf(-acc));
  }
}

// ---------------- merged weight transforms to bf16 ----------------
__global__ __launch_bounds__(256) void k_wprep(const float* __restrict__ w1,
    const float* __restrict__ wsc, const float* __restrict__ w2,
    u16* __restrict__ w1t, u16* __restrict__ wsct, u16* __restrict__ w2t){
  int bx = blockIdx.x, ci = threadIdx.x;
  if (bx < 2304){
    int co = bx / 9, t = bx - co*9;
    w1t[(size_t)co*2304 + t*256 + ci] = f2bf(w1[(size_t)(co*256+ci)*9 + t]);
  } else if (bx < 2560){
    int i = (bx-2304)*256 + ci;
    wsct[i] = f2bf(wsc[i]);
  } else {
    int i = (bx-2560)*256 + ci;
    w2t[i] = f2bf(w2[i]);
  }
}

// ---------------- zero the 1-px halo ring of padded xm ----------------
__global__ __launch_bounds__(256) void k_halo(u16* __restrict__ xm){
  int b = blockIdx.x, tid = threadIdx.x;
  uint4 zq = {0u,0u,0u,0u};
  for (int i = tid; i < 260; i += 256){
    int row, col;
    if (i < 66){ row = 0; col = i; }
    else if (i < 132){ row = 65; col = i - 66; }
    else { int j = i - 132; row = 1 + (j >> 1); col = (j & 1) * 65; }
    uint4* p = (uint4*)(xm + ((size_t)b*PIMG + row*66 + col)*256);
    #pragma unroll
    for (int q=0;q<32;q++) p[q] = zq;
  }
}

// ---------------- xm = x*mod, NCHW f32 -> padded NHWC bf16 [16][66][66][256] ----------------
__global__ __launch_bounds__(256) void k_xm(const float* __restrict__ x, const float* __restrict__ modb,
                                            u16* __restrict__ xm){
  __shared__ __attribute__((aligned(16))) u16 tile[64*266];
  int pt = blockIdx.x, ct = blockIdx.y, tid = threadIdx.x;
  int b = pt >> 4;
  int rem = (pt & 15) << 8;
  int C0 = ct << 6;
  {
    int c = tid >> 2, q = tid & 3;
    const float* xp = x + ((size_t)(b*256 + C0 + c))*HW + rem;
    float mv = modb[b*256 + C0 + c];
    #pragma unroll
    for (int k=0;k<16;k++){
      int pos = q*64 + k*4;
      float4 v = *(const float4*)(xp + pos);
      u32 w0 = (u32)f2bf(v.x*mv) | ((u32)f2bf(v.y*mv) << 16);
      u32 w1 = (u32)f2bf(v.z*mv) | ((u32)f2bf(v.w*mv) << 16);
      u32* dst = (u32*)&tile[c*266 + pos];
      dst[0] = w0; dst[1] = w1;
    }
  }
  __syncthreads();
  {
    int g = tid & 7, p0 = tid >> 3;
    #pragma unroll
    for (int k=0;k<8;k++){
      int pos = p0 + k*32;
      u32 v0 = tile[(g*8+0)*266 + pos], v1 = tile[(g*8+1)*266 + pos];
      u32 v2 = tile[(g*8+2)*266 + pos], v3 = tile[(g*8+3)*266 + pos];
      u32 v4 = tile[(g*8+4)*266 + pos], v5 = tile[(g*8+5)*266 + pos];
      u32 v6 = tile[(g*8+6)*266 + pos], v7 = tile[(g*8+7)*266 + pos];
      uint4 pk;
      pk.x = v0 | (v1<<16); pk.y = v2 | (v3<<16);
      pk.z = v4 | (v5<<16); pk.w = v6 | (v7<<16);
      int gp = rem + pos;
      int h = gp >> 6, w = gp & 63;
      *(uint4*)(xm + ((size_t)b*PIMG + (h+1)*66 + (w+1))*256 + C0 + g*8) = pk;
    }
  }
}

// ---------------- 256x256 8-wave GEMM, 8-phase BK=64 (m201 class) ----------------
// R12: + XCD-aware bijective blockIdx swizzle (T1, m192). R6 counters: padded conv
// FETCH 71->100.7MB, dur 80->91us -- round-robin bid%8 puts halo-sharing neighbor
// tiles on DIFFERENT XCD L2s; per-XCD working set 32 x ~200KB = 6.5MB > 4MB L2.
// Swizzle mt=(bx&7)*32+(bx>>3): each XCD owns 32 contiguous m-tiles (2 images),
// halo reuse lands in-L2, per-XCD unique ~4.5MB. nwg=256 % 8 == 0 -> bijective.
template<int NTAPS, int APAD>
__global__ __launch_bounds__(512, 2) void k_gemm8p(const u16* __restrict__ A,
    const u16* __restrict__ Bw, u16* __restrict__ y,
    float* __restrict__ psum, float* __restrict__ psq){
  constexpr int KTOT = NTAPS*256;
  constexpr int NT = KTOT/64;          // K-tiles (BK=64)
  constexpr int NI = NT/2;             // iterations (2 tiles each)
  __shared__ __attribute__((aligned(16))) u16 SH[65536];   // A [0,32K), B [32K,64K) u16
  int tid = threadIdx.x;
  int lane = tid & 63, wave = tid >> 6;
  int wm = wave >> 2, wn = wave & 3;
  int l15 = lane & 15, quad = lane >> 4;
  int bx = blockIdx.x;
  int mt = ((bx & 7) << 5) | (bx >> 3);   // XCD swizzle: contiguous 32-tile chunk per XCD
  int P0 = mt*256;

  // read-side: phys chunk = (ks*4+quad) ^ (row&7); row&7 == l15&7
  int s3  = l15 & 7;
  int kx0 = ((quad)     ^ s3) * 8;
  int kx1 = ((4 | quad) ^ s3) * 8;
  int aBase = wm*8192 + l15*64;                                  // + d + qm*4096 + fi*1024
  int bBase = 32768 + (wn>>1)*8192 + (wn&1)*4096 + l15*64;       // + d + fj*1024

  // staging decode: linear chunk = tid -> row=tid>>3, logical chunk c0=pchunk^(row&7)
  int r0  = tid >> 3;
  int csrc = ((tid & 7) ^ (r0 & 7)) * 8;

  // fixed per-thread source voffsets (u16 units)
  auto pvoff = [&](int pos)->int{
    if constexpr (APAD){
      int b_ = pos >> 12, rm = pos & 4095;
      return (b_*PIMG + ((rm>>6)+1)*66 + (rm&63)+1)*256 + csrc;
    } else {
      return pos*256 + csrc;
    }
  };
  const int vA00 = pvoff(P0 + r0),        vA01 = pvoff(P0 + 64 + r0);
  const int vA10 = pvoff(P0 + 128 + r0),  vA11 = pvoff(P0 + 192 + r0);
  const int vB00 = (r0)*KTOT + csrc,       vB01 = (64 + r0)*KTOT + csrc;
  const int vB10 = (128 + r0)*KTOT + csrc, vB11 = (192 + r0)*KTOT + csrc;

  f32x4 acc[8][4];
  f32x4 zz = {0.f,0.f,0.f,0.f};
  #pragma unroll
  for (int i=0;i<8;i++)
    #pragma unroll
    for (int j=0;j<4;j++) acc[i][j] = zz;

  auto stageA = [&](int t, int ah){
    int base = (t&1)*16384 + ah*8192;
    int uoff;
    if constexpr (NTAPS == 9){
      int tap = t >> 2, t3 = (tap*11) >> 5;           // t3 = tap/3
      uoff = (tap + 63*t3 - 67)*256 + (t&3)*64;       // padded tap delta * 256 + koff
    } else {
      uoff = t*64;
    }
    GLL16(A + uoff + (ah ? vA10 : vA00), SH + base + tid*8);
    GLL16(A + uoff + (ah ? vA11 : vA01), SH + base + 4096 + tid*8);
  };
  auto stageB = [&](int t, int bh){
    int base = 32768 + (t&1)*16384 + bh*8192;
    int uoff = t*64;
    GLL16(Bw + uoff + (bh ? vB10 : vB00), SH + base + tid*8);
    GLL16(Bw + uoff + (bh ? vB11 : vB01), SH + base + 4096 + tid*8);
  };

  // prologue: T0 fully + T1.A halves (12 loads); wait T0 (leave 4 in flight)
  stageA(0,0); stageA(0,1); stageB(0,0); stageB(0,1);
  stageA(1,0); stageA(1,1);
  VM4();
  BAR();

  bf16x8 aLo[2][4], aHi[2][4], bLo[2][2], bHi[2][2];

  for (int n=0; n<NI; ++n){
    const int t1 = 2*n+1;
    const bool pre = (n+1 < NI);
    // ---- p1: read T0 aLo+bLo (12 rd); stage T1.B0 ----
    RDA(aLo, 0, 0); RDB(bLo, 0, 0);
    stageB(t1, 0);
    BAR();
    SP1(); MMQ(aLo, bLo, 0, 0); SP0();
    BAR();
    // ---- p2: read aHi; stage T1.B1 ----
    RDA(aHi, 0, 4096);
    stageB(t1, 1);
    BAR();
    SP1(); MMQ(aHi, bLo, 4, 0); SP0();
    BAR();
    // ---- p3: read bHi; stage T2.A0 ----
    RDB(bHi, 0, 2048);
    if (pre) stageA(t1+1, 0);
    BAR();
    SP1(); MMQ(aHi, bHi, 4, 2); SP0();
    BAR();
    // ---- p4: stage T2.A1; VM4 (T1 landed) ----
    if (pre){ stageA(t1+1, 1); VM4(); } else { VM0(); }
    BAR();
    SP1(); MMQ(aLo, bHi, 0, 2); SP0();
    BAR();
    // ---- p5: read T1 aLo+bLo (buf1); stage T2.B0 ----
    RDA(aLo, 16384, 0); RDB(bLo, 16384, 0);
    if (pre) stageB(t1+1, 0);
    BAR();
    SP1(); MMQ(aLo, bLo, 0, 0); SP0();
    BAR();
    // ---- p6: read aHi; stage T2.B1 ----
    RDA(aHi, 16384, 4096);
    if (pre) stageB(t1+1, 1);
    BAR();
    SP1(); MMQ(aHi, bLo, 4, 0); SP0();
    BAR();
    // ---- p7: read bHi; stage T3.A0 ----
    RDB(bHi, 16384, 2048);
    if (pre) stageA(t1+2, 0);
    BAR();
    SP1(); MMQ(aHi, bHi, 4, 2); SP0();
    BAR();
    // ---- p8: stage T3.A1; VM4 (T2 landed) ----
    if (pre){ stageA(t1+2, 1); VM4(); }
    BAR();
    SP1(); MMQ(aLo, bHi, 0, 2); SP0();
    BAR();
  }

  // ---- epilogue: y stores + per-mtile channel partials ----
  #pragma unroll
  for (int i=0;i<8;i++){
    int m = wm*128 + i*16 + quad*4;
    #pragma unroll
    for (int j=0;j<4;j++){
      int n = wn*64 + j*16 + l15;
      size_t base = ((size_t)(P0 + m))*CH + n;
      #pragma unroll
      for (int r=0;r<4;r++)
        y[base + (size_t)r*CH] = f2bf(acc[i][j][r]);
    }
  }
  float* SHf = (float*)SH;   // safe: loop-end barrier passed, vmcnt drained
  #pragma unroll
  for (int j=0;j<4;j++){
    float a=0.f, b=0.f;
    #pragma unroll
    for (int i=0;i<8;i++)
      #pragma unroll
      for (int r=0;r<4;r++){ float v = acc[i][j][r]; a += v; b += v*v; }
    a += __shfl_xor(a,16); b += __shfl_xor(b,16);
    a += __shfl_xor(a,32); b += __shfl_xor(b,32);
    if (quad==0){
      int idx = ((wave*4 + j)*16 + l15)*2;
      SHf[idx] = a; SHf[idx+1] = b;
    }
  }
  __syncthreads();
  if (tid < 256){
    int n = tid; int wnn = n>>6; int j = (n>>4)&3; int li = n&15;
    int i0 = (((wnn)*4 + j)*16 + li)*2;        // wm=0 wave = wn
    int i1 = (((4+wnn)*4 + j)*16 + li)*2;      // wm=1 wave = 4+wn
    psum[(size_t)n*NMT + mt] = SHf[i0] + SHf[i1];
    psq [(size_t)n*NMT + mt] = SHf[i0+1] + SHf[i1+1];
  }
}

// ---------------- BN stat finalize: one block per channel, coalesced ----------------
__global__ __launch_bounds__(64) void k_bnstat(const float* __restrict__ psum, const float* __restrict__ psq,
    const float* __restrict__ g, const float* __restrict__ be,
    float* __restrict__ scale, float* __restrict__ shift){
  int c = blockIdx.x, t = threadIdx.x;
  const float* ps = psum + (size_t)c*NMT;
  const float* pq = psq  + (size_t)c*NMT;
  float s=0.f, q=0.f;
  #pragma unroll
  for (int i=0;i<4;i++){ s += ps[t + i*64]; q += pq[t + i*64]; }
  #pragma unroll
  for (int off=32; off>0; off>>=1){
    s += __shfl_down(s, off);
    q += __shfl_down(q, off);
  }
  if (t == 0){
    float mean = s * (1.f/65536.f);
    float var  = q * (1.f/65536.f) - mean*mean;
    float rstd = rsqrtf(var + 1e-5f);
    float sc = g[c]*rstd;
    scale[c] = sc;
    shift[c] = be[c] - mean*sc;
  }
}

// ---------------- bb1 = silu(bn1(y1)) elementwise on NHWC bf16 ----------------
__global__ __launch_bounds__(256) void k_bb(const u16* __restrict__ y1, const float* __restrict__ sc1,
    const float* __restrict__ sh1, u16* __restrict__ bb){
  __shared__ float sc[256], sh[256];
  int tid = threadIdx.x;
  sc[tid] = sc1[tid]; sh[tid] = sh1[tid];
  __syncthreads();
  size_t i = ((size_t)blockIdx.x*256 + tid)*8;
  int c0 = (int)(i & 255);
  uint4 v = *(const uint4*)(y1 + i);
  u32 a[4] = {v.x, v.y, v.z, v.w};
  u32 o[4];
  #pragma unroll
  for (int p=0;p<4;p++){
    float zl = sc[c0+2*p]*bflo(a[p]) + sh[c0+2*p];
    float zh = sc[c0+2*p+1]*bfhi(a[p]) + sh[c0+2*p+1];
    float ol = zl/(1.f+__expf(-zl));
    float oh = zh/(1.f+__expf(-zh));
    o[p] = (u32)f2bf(ol) | ((u32)f2bf(oh) << 16);
  }
  uint4 w; w.x=o[0]; w.y=o[1]; w.z=o[2]; w.w=o[3];
  *(uint4*)(bb + i) = w;
}

// ---------------- out = silu(bn2(y2)+bns(ysc)), NHWC bf16 -> NCHW f32 ----------------
__global__ __launch_bounds__(256) void k_final(const u16* __restrict__ y2, const u16* __restrict__ ysc,
    const float* __restrict__ sc2, const float* __restrict__ sh2,
    const float* __restrict__ scs, const float* __restrict__ shs,
    float* __restrict__ out){
  __shared__ __attribute__((aligned(16))) float tile[64*257];
  __shared__ float l2s[64], l2h[64], lss[64], lsh[64];
  int pt = blockIdx.x, ct = blockIdx.y, tid = threadIdx.x;
  int C0 = ct << 6;
  if (tid < 64){ l2s[tid]=sc2[C0+tid]; l2h[tid]=sh2[C0+tid]; lss[tid]=scs[C0+tid]; lsh[tid]=shs[C0+tid]; }
  __syncthreads();
  size_t P0 = (size_t)pt * 256;
  int b = pt >> 4; int rem = (pt & 15) << 8;
  {
    int g = tid & 7, p0 = tid >> 3;
    for (int k=0;k<8;k++){
      int pos = p0 + k*32;
      size_t off = (P0+pos)*CH + C0 + g*8;
      uint4 va = *(const uint4*)(y2 + off);
      uint4 vb = *(const uint4*)(ysc + off);
      u32 aa[4] = {va.x,va.y,va.z,va.w};
      u32 bv[4] = {vb.x,vb.y,vb.z,vb.w};
      #pragma unroll
      for (int p=0;p<4;p++){
        int c = g*8 + 2*p;
        float z0 = l2s[c]*bflo(aa[p]) + l2h[c] + lss[c]*bflo(bv[p]) + lsh[c];
        float z1 = l2s[c+1]*bfhi(aa[p]) + l2h[c+1] + lss[c+1]*bfhi(bv[p]) + lsh[c+1];
        tile[c*257 + pos]     = z0/(1.f+__expf(-z0));
        tile[(c+1)*257 + pos] = z1/(1.f+__expf(-z1));
      }
    }
  }
  __syncthreads();
  {
    int c = tid >> 2, q = tid & 3;
    float* op = out + ((size_t)(b*256 + C0 + c))*HW + rem;
    #pragma unroll
    for (int k=0;k<16;k++){
      int pos = q*64 + k*4;
      float4 v;
      v.x = tile[c*257 + pos];
      v.y = tile[c*257 + pos + 1];
      v.z = tile[c*257 + pos + 2];
      v.w = tile[c*257 + pos + 3];
      *(float4*)(op + pos) = v;
    }
  }
}

extern "C" void kernel_launch(void* const* d_in, const int* in_sizes, int n_in,
                              void* d_out, int out_size, void* d_ws, size_t ws_size,
                              hipStream_t stream){
  const float* x     = (const float*)d_in[0];
  const float* dce   = (const float*)d_in[1];
  const float* w_dce = (const float*)d_in[2];
  const float* b_dce = (const float*)d_in[3];
  const float* w_ch  = (const float*)d_in[4];
  const float* w_sh  = (const float*)d_in[5];
  const float* b_sh  = (const float*)d_in[6];
  const float* w_ex  = (const float*)d_in[7];
  const float* b_ex  = (const float*)d_in[8];
  const float* w_c1  = (const float*)d_in[9];
  const float* g1    = (const float*)d_in[10];
  const float* be1   = (const float*)d_in[11];
  const float* w_c2  = (const float*)d_in[12];
  const float* g2    = (const float*)d_in[13];
  const float* be2   = (const float*)d_in[14];
  const float* w_s   = (const float*)d_in[15];
  const float* gs    = (const float*)d_in[16];
  const float* bes   = (const float*)d_in[17];
  float* out = (float*)d_out;
  char* ws = (char*)d_ws;

  const size_t NB  = (size_t)NPOS*CH*2;        // 32 MiB per bf16 tensor
  const size_t XMB = (size_t)16*PIMG*CH*2;     // padded xm, ~35.7 MiB
  u16* xm  = (u16*)(ws);
  u16* y1  = (u16*)(ws + XMB);
  u16* ysc = (u16*)(ws + XMB + NB);
  u16* bb  = (u16*)(ws + XMB + 2*NB);
  char* p = ws + XMB + 3*NB;
  u16* w1t   = (u16*)p; p += (size_t)256*2304*2;
  u16* wsct  = (u16*)p; p += (size_t)256*256*2;
  u16* w2t   = (u16*)p; p += (size_t)256*256*2;
  float* statsx = (float*)p; p += (size_t)16*256*9*4;
  float* modb   = (float*)p; p += (size_t)16*256*4;
  float* p1s = (float*)p; p += (size_t)MT*256*4;
  float* p1q = (float*)p; p += (size_t)MT*256*4;
  float* pss = (float*)p; p += (size_t)MT*256*4;
  float* psqv= (float*)p; p += (size_t)MT*256*4;
  float* p2s = (float*)p; p += (size_t)MT*256*4;
  float* p2q = (float*)p; p += (size_t)MT*256*4;
  float* bn1sc = (float*)p; p += 1024;
  float* bn1sh = (float*)p; p += 1024;
  float* bnssc = (float*)p; p += 1024;
  float* bnssh = (float*)p; p += 1024;
  float* bn2sc = (float*)p; p += 1024;
  float* bn2sh = (float*)p; p += 1024;

  k_halo<<<16, 256, 0, stream>>>(xm);
  k_statsx<<<4096, 256, 0, stream>>>(x, statsx);
  k_wprep<<<2816, 256, 0, stream>>>(w_c1, w_s, w_c2, w1t, wsct, w2t);
  k_gate<<<16, 256, 0, stream>>>(dce, statsx, w_ch, w_dce, b_dce, w_sh, b_sh, w_ex, b_ex, modb);
  k_xm<<<dim3(256,4), 256, 0, stream>>>(x, modb, xm);
  k_gemm8p<9,1><<<256, 512, 0, stream>>>(xm, w1t, y1, p1s, p1q);
  k_bnstat<<<256, 64, 0, stream>>>(p1s, p1q, g1, be1, bn1sc, bn1sh);
  k_bb<<<8192, 256, 0, stream>>>(y1, bn1sc, bn1sh, bb);
  k_gemm8p<1,1><<<256, 512, 0, stream>>>(xm, wsct, ysc, pss, psqv);
  k_bnstat<<<256, 64, 0, stream>>>(pss, psqv, gs, bes, bnssc, bnssh);
  k_gemm8p<1,0><<<256, 512, 0, stream>>>(bb, w2t, y1 /*=y2*/, p2s, p2q);
  k_bnstat<<<256, 64, 0, stream>>>(p2s, p2q, g2, be2, bn2sc, bn2sh);
  k_final<<<dim3(256,4), 256, 0, stream>>>(y1, ysc, bn2sc, bn2sh, bnssc, bnssh, out);
}